// Round 16
// baseline (249.587 us; speedup 1.0000x reference)
//
#include <hip/hip_runtime.h>

using bf16x8 = __attribute__((ext_vector_type(8))) short;
using f32x4  = __attribute__((ext_vector_type(4))) float;
using f32x2  = __attribute__((ext_vector_type(2))) float;

constexpr int Bb = 8, Nn = 8192, Mm = 2048, C1 = 128, C2 = 256, Hh = 256, K1 = 384;
constexpr int KT1 = K1 / 32;   // 12 k-tiles for GEMM1
constexpr int KT2 = Hh / 32;   // 8 k-tiles for GEMM2
constexpr int RT = Hh / 16;    // 16 row-tiles
constexpr int NTL = 2;         // R16: col-tiles per fused block (64->32 cols)
constexpr int NQ = 4;          // nn: NQ=4 gated = 64.0us, best of 6 variants (R8..R14)
constexpr int MQ = Mm / NQ;    // 512 candidates per quarter

__device__ __forceinline__ short f2bf(float x) {  // RNE float->bf16
  union { float f; unsigned u; } v; v.f = x;
  unsigned r = v.u + 0x7fff + ((v.u >> 16) & 1);
  return (short)(r >> 16);
}

// packed RNE float2 -> 2x bf16 in one dword (hw instr when available)
__device__ __forceinline__ unsigned pk2bf(float a, float b) {
#if defined(__has_builtin) && __has_builtin(__builtin_amdgcn_cvt_pk_bf16_f32)
  typedef __attribute__((ext_vector_type(2))) __bf16 bf2_t;
  bf2_t r = __builtin_amdgcn_cvt_pk_bf16_f32(a, b);
  union { bf2_t v; unsigned u; } cvt; cvt.v = r;
  return cvt.u;
#else
  return (unsigned)(unsigned short)f2bf(a) | ((unsigned)(unsigned short)f2bf(b) << 16);
#endif
}

// unpack a dword holding 2 bf16 (lo = element 2i, hi = element 2i+1)
__device__ __forceinline__ float bflo(unsigned d) { return __uint_as_float(d << 16); }
__device__ __forceinline__ float bfhi(unsigned d) { return __uint_as_float(d & 0xffff0000u); }

// packed fp32 (CDNA3+). Lessons: feed ONLY from direct f32x2 loads (R9);
// two-pass recompute loses (R10); v_pk fp32 is throughput-neutral vs scalar
// (R13); 2-queries/thread loses TLP (R14). NQ=4 gated one-pass is the floor.
__device__ __forceinline__ f32x2 pk_add(f32x2 a, f32x2 b) {
  f32x2 d; asm("v_pk_add_f32 %0, %1, %2" : "=v"(d) : "v"(a), "v"(b)); return d;
}
__device__ __forceinline__ f32x2 pk_mul(f32x2 a, f32x2 b) {
  f32x2 d; asm("v_pk_mul_f32 %0, %1, %2" : "=v"(d) : "v"(a), "v"(b)); return d;
}
__device__ __forceinline__ f32x2 pk_fma(f32x2 a, f32x2 b, f32x2 c) {
  f32x2 d; asm("v_pk_fma_f32 %0, %1, %2, %3" : "=v"(d) : "v"(a), "v"(b), "v"(c)); return d;
}

// stable 2-list merge of sorted triples; ties prefer list a (lower global idx)
__device__ __forceinline__ void merge3(float a0, float a1, float a2, int A0, int A1, int A2,
                                       float b0, float b1, float b2, int B0, int B1, int B2,
                                       float& m0, float& m1, float& m2,
                                       int& j0, int& j1, int& j2) {
  bool ta = a0 <= b0;
  m0 = ta ? a0 : b0; j0 = ta ? A0 : B0;
  float na0 = ta ? a1 : a0, na1 = ta ? a2 : a1;
  int   nA0 = ta ? A1 : A0, nA1 = ta ? A2 : A1;
  float nb0 = ta ? b0 : b1, nb1 = ta ? b1 : b2;
  int   nB0 = ta ? B0 : B1, nB1 = ta ? B1 : B2;
  ta = na0 <= nb0;
  m1 = ta ? na0 : nb0; j1 = ta ? nA0 : nB0;
  float ma0 = ta ? na1 : na0; int mA0 = ta ? nA1 : nA0;
  float mb0 = ta ? nb0 : nb1; int mB0 = ta ? nB0 : nB1;
  ta = ma0 <= mb0;
  m2 = ta ? ma0 : mb0; j2 = ta ? mA0 : mB0;
}

// ------------- prep: kf transpose->bf16 (blocks 0..4095) + W frag prep -------------
// NOTE: prep, nn, fused stay SEPARATE kernels (R5/R6: fusing roles into one grid
// serialized the nn phase behind the transpose blocks, +40 us; launch overhead is
// fixed ~85 us regardless of kernel count — do not re-fuse).
__global__ __launch_bounds__(256) void prep_all_k(const float* __restrict__ kf,
                                                  short* __restrict__ kfTb,
                                                  const float* __restrict__ W1,
                                                  const float* __restrict__ W2,
                                                  short* __restrict__ W1f,
                                                  short* __restrict__ W2f) {
  __shared__ float tile[32][33];
  int bid = blockIdx.x, tid = threadIdx.x;
  if (bid < 4096) {  // transpose role: (B,C2,Mm) f32 -> (B,Mm,C2) bf16
    int cx = bid & 63, ry = (bid >> 6) & 7, z = bid >> 9;
    const float* src = kf + (size_t)z * C2 * Mm;
    short* dst = kfTb + (size_t)z * Mm * C2;
    int c0 = cx * 32, r0 = ry * 32;  // c0: point base, r0: channel base
    int tx = tid & 31, ty = tid >> 5;
#pragma unroll
    for (int rr = ty; rr < 32; rr += 8)
      tile[rr][tx] = src[(size_t)(r0 + rr) * Mm + c0 + tx];
    __syncthreads();
#pragma unroll
    for (int cc = ty; cc < 32; cc += 8)
      dst[(size_t)(c0 + cc) * C2 + r0 + tx] = f2bf(tile[tx][cc]);
    return;
  }
  // W-prep role: A-frag planes (lane holds A[m=lane&15][k0..k0+7], k0=(lane>>4)*8)
  int id = (bid - 4096) * 256 + tid;
  const int n1 = KT1 * RT * 64;
  const int n2 = KT2 * RT * 64;
  if (id < n1) {
    int lane = id & 63, t = id >> 6;
    int kt = t / RT, rt = t % RT;
    int m = rt * 16 + (lane & 15), k0 = kt * 32 + (lane >> 4) * 8;
    bf16x8 f;
#pragma unroll
    for (int j = 0; j < 8; ++j) f[j] = f2bf(W1[(size_t)m * K1 + k0 + j]);
    *(bf16x8*)(W1f + (size_t)id * 8) = f;
  } else if (id < n1 + n2) {
    int id2 = id - n1;
    int lane = id2 & 63, t = id2 >> 6;
    int kt = t / RT, rt = t % RT;
    int m = rt * 16 + (lane & 15), k0 = kt * 32 + (lane >> 4) * 8;
    bf16x8 f;
#pragma unroll
    for (int j = 0; j < 8; ++j) f[j] = f2bf(W2[(size_t)m * Hh + k0 + j]);
    *(bf16x8*)(W2f + (size_t)id2 * 8) = f;
  }
}

// ------------- three_nn over a quarter of the candidate set (R8-verbatim) -------------
// grid: b(8) x nblk(32) x q(4) = 1024 blocks of 256 -> 16 waves/CU (4/SIMD).
// Measured 64.0us (R8/R15) — best of 6 variants. Do not re-tune.
__global__ __launch_bounds__(256) void nn_quarter_k(const float* __restrict__ unknown,
                                                    const float* __restrict__ known,
                                                    float* __restrict__ pd,
                                                    int* __restrict__ pi) {
  __shared__ float kx[MQ], ky[MQ], kz[MQ];
  int bid = blockIdx.x;
  int b = bid >> 7, rem = bid & 127;
  int q = rem & 3, nblk = rem >> 2;
  int n = nblk * 256 + threadIdx.x;
  const float* kb = known + ((size_t)b * Mm + q * MQ) * 3;
  for (int p = threadIdx.x; p < MQ; p += 256) {
    kx[p] = kb[3 * p]; ky[p] = kb[3 * p + 1]; kz[p] = kb[3 * p + 2];
  }
  __syncthreads();

  size_t ui = ((size_t)b * Nn + n) * 3;
  float ux = unknown[ui], uy = unknown[ui + 1], uz = unknown[ui + 2];
  float d0 = 1e30f, d1 = 1e30f, d2 = 1e30f;
  int i0 = 0, i1 = 0, i2 = 0;
  int gbase = q * MQ;

  // broadcast negated query into packed pairs (once per thread)
  f32x2 nux = { -ux, -ux }, nuy = { -uy, -uy }, nuz = { -uz, -uz };

#define NN_INS(dd, qq)                                                  \
  {                                                                     \
    if (__any((dd) < d2)) { /* wave-uniform skip of the insert chain */ \
      int jm = gbase + jb + (qq);                                       \
      bool c0 = (dd) < d0, c1 = (dd) < d1, c2 = (dd) < d2;              \
      d2 = c1 ? d1 : (c2 ? (dd) : d2); i2 = c1 ? i1 : (c2 ? jm : i2);   \
      d1 = c0 ? d0 : (c1 ? (dd) : d1); i1 = c0 ? i0 : (c1 ? jm : i1);   \
      d0 = c0 ? (dd) : d0;             i0 = c0 ? jm : i0;               \
    }                                                                   \
  }

  const f32x2* kx2 = (const f32x2*)kx;
  const f32x2* ky2 = (const f32x2*)ky;
  const f32x2* kz2 = (const f32x2*)kz;
  for (int jb = 0; jb < MQ; jb += 4) {
    int h = jb >> 1;
    f32x2 xa = kx2[h], xb = kx2[h + 1];
    f32x2 ya = ky2[h], yb = ky2[h + 1];
    f32x2 za = kz2[h], zb = kz2[h + 1];
    // dd = (k-u)^2 summed; (k-u)^2 == (u-k)^2 bit-exact in fp32
    f32x2 dxa = pk_add(xa, nux), dya = pk_add(ya, nuy), dza = pk_add(za, nuz);
    f32x2 dda = pk_fma(dza, dza, pk_fma(dya, dya, pk_mul(dxa, dxa)));
    f32x2 dxb = pk_add(xb, nux), dyb = pk_add(yb, nuy), dzb = pk_add(zb, nuz);
    f32x2 ddb = pk_fma(dzb, dzb, pk_fma(dyb, dyb, pk_mul(dxb, dxb)));
    NN_INS(dda.x, 0)
    NN_INS(dda.y, 1)
    NN_INS(ddb.x, 2)
    NN_INS(ddb.y, 3)
  }
#undef NN_INS

  size_t o = (((size_t)b * Nn + n) * NQ + q) * 3;
  pd[o] = d0; pd[o + 1] = d1; pd[o + 2] = d2;
  pi[o] = i0; pi[o + 1] = i1; pi[o + 2] = i2;
}

// ------------- fused: 4-way merge -> gather+concat -> MLP1 -> MLP2 -> out -------------
// R16: 32-col blocks. Fused was GRID-limited at 4 blocks/CU (1024 blocks; R11
// counters: MfmaUtil 9.5%, VALUBusy 16%, HBM 17% — pure latency). Grid 2048 ->
// 8 blocks/CU; LDS 16KB (6-plane x NTL=2 F buf filled twice + 16KB Hs overlay).
// Gather: thread owns point bt*32+(wv&1)*16+col; wave-pairs {0,1}/{2,3} cover
// even/odd kt. MFMA tiles acc[4][NTL]. Numerics bit-identical to R15.
__global__ __launch_bounds__(256) void fused_gemm_k(
    const float* __restrict__ uf, const short* __restrict__ kfTb,
    const short* __restrict__ W1f, const float* __restrict__ b1,
    const short* __restrict__ W2f, const float* __restrict__ b2,
    const float* __restrict__ pd, const int* __restrict__ pi,
    float* __restrict__ out) {
  __shared__ short Fs[KT2 * NTL * 64 * 8];  // 16KB: Hs for K2; head 12KB = 6-plane F buf
  short* Hs = Fs;
  int bid = blockIdx.x;
  int b = bid >> 8, bt = bid & 255;  // n0 = bt*32
  int tid = threadIdx.x, lane = tid & 63, wv = tid >> 6;
  int quad = lane >> 4, col = lane & 15;
  const int ntl = wv & 1;                    // this thread's col-tile (gather role)
  const int kph = wv >> 1;                   // kt parity within wave-pair
  const int nq = bt * 32 + ntl * 16 + col;   // this thread's point

  // ---- merge: in-register 4-way NN merge (tree of 3 stable merges, R8 code).
  // Temps t-prefixed (R10 lesson: unprefixed names shadowed constexpr C1/C2).
  float w0, w1, w2;
  int g0, g1, g2;
  {
    size_t pbase = (size_t)(b * Nn + nq) * (NQ * 3);  // stride 12 floats (48B), 16B-aligned
    float4 da = *(const float4*)&pd[pbase];
    float4 db = *(const float4*)&pd[pbase + 4];
    float4 dc = *(const float4*)&pd[pbase + 8];
    int4 ia = *(const int4*)&pi[pbase];
    int4 ib = *(const int4*)&pi[pbase + 4];
    int4 ic = *(const int4*)&pi[pbase + 8];
    float t0, t1, t2, u0, u1, u2, m0, m1, m2;
    int T0, T1, T2, U0, U1, U2;
    merge3(da.x, da.y, da.z, ia.x, ia.y, ia.z,
           da.w, db.x, db.y, ia.w, ib.x, ib.y, t0, t1, t2, T0, T1, T2);
    merge3(db.z, db.w, dc.x, ib.z, ib.w, ic.x,
           dc.y, dc.z, dc.w, ic.y, ic.z, ic.w, u0, u1, u2, U0, U1, U2);
    merge3(t0, t1, t2, T0, T1, T2, u0, u1, u2, U0, U1, U2,
           m0, m1, m2, g0, g1, g2);
    float s0 = sqrtf(m0), s1 = sqrtf(m1), s2 = sqrtf(m2);
    float r0 = 1.f / (s0 + 1e-8f), r1 = 1.f / (s1 + 1e-8f), r2 = 1.f / (s2 + 1e-8f);
    float rs = 1.f / (r0 + r1 + r2);
    w0 = r0 * rs; w1 = r1 * rs; w2 = r2 * rs;
  }
  const short* kfb = kfTb + (size_t)b * Mm * C2;

#define GATHER_KT(kt, plane)                                                  \
  {                                                                           \
    int c0 = (kt) * 32 + quad * 8;                                            \
    uint4 q0 = *(const uint4*)&kfb[(size_t)g0 * C2 + c0];                     \
    uint4 q1 = *(const uint4*)&kfb[(size_t)g1 * C2 + c0];                     \
    uint4 q2 = *(const uint4*)&kfb[(size_t)g2 * C2 + c0];                     \
    float e0 = w0 * bflo(q0.x) + w1 * bflo(q1.x) + w2 * bflo(q2.x);           \
    float e1 = w0 * bfhi(q0.x) + w1 * bfhi(q1.x) + w2 * bfhi(q2.x);           \
    float e2 = w0 * bflo(q0.y) + w1 * bflo(q1.y) + w2 * bflo(q2.y);           \
    float e3 = w0 * bfhi(q0.y) + w1 * bfhi(q1.y) + w2 * bfhi(q2.y);           \
    float e4 = w0 * bflo(q0.z) + w1 * bflo(q1.z) + w2 * bflo(q2.z);           \
    float e5 = w0 * bfhi(q0.z) + w1 * bfhi(q1.z) + w2 * bfhi(q2.z);           \
    float e6 = w0 * bflo(q0.w) + w1 * bflo(q1.w) + w2 * bflo(q2.w);           \
    float e7 = w0 * bfhi(q0.w) + w1 * bfhi(q1.w) + w2 * bfhi(q2.w);           \
    uint4 packed;                                                             \
    packed.x = pk2bf(e0, e1); packed.y = pk2bf(e2, e3);                       \
    packed.z = pk2bf(e4, e5); packed.w = pk2bf(e6, e7);                       \
    *(uint4*)&Fs[(((plane) * NTL + ntl) * 64 + lane) * 8] = packed;           \
  }

  // ---- Phase A-1: planes 0..5 <- kt 0..5 (wave-pair covers 2 kt per step)
#pragma unroll
  for (int it = 0; it < 3; ++it) {
    int ktg = it * 2 + kph;
    GATHER_KT(ktg, ktg)
  }
  __syncthreads();  // B1: F half 1 ready

  // ---- K1a: kt 0..5
  f32x4 acc[4][NTL];
#pragma unroll
  for (int r = 0; r < 4; ++r)
#pragma unroll
    for (int c = 0; c < NTL; ++c) acc[r][c] = (f32x4){0.f, 0.f, 0.f, 0.f};

  for (int kt = 0; kt < 6; ++kt) {
    bf16x8 Afr[4], Bfr[NTL];
#pragma unroll
    for (int r = 0; r < 4; ++r)
      Afr[r] = *(const bf16x8*)(W1f + ((size_t)(kt * RT + wv * 4 + r) * 64 + lane) * 8);
#pragma unroll
    for (int c = 0; c < NTL; ++c)
      Bfr[c] = *(const bf16x8*)&Fs[((kt * NTL + c) * 64 + lane) * 8];
#pragma unroll
    for (int r = 0; r < 4; ++r)
#pragma unroll
      for (int c = 0; c < NTL; ++c)
        acc[r][c] = __builtin_amdgcn_mfma_f32_16x16x32_bf16(Afr[r], Bfr[c], acc[r][c], 0, 0, 0);
  }
  __syncthreads();  // B2: half-1 reads done; planes reusable

  // ---- Phase A-2: kt 6,7 -> planes 0,1; uf kt 8..11 -> planes 2..5
  GATHER_KT(6 + kph, kph)
#pragma unroll
  for (int it = 0; it < 2; ++it) {
    int kt = 8 + it * 2 + kph;       // uf k-tile
    int c1 = (kt - 8) * 32 + quad * 8;
    float e[8];
#pragma unroll
    for (int j = 0; j < 8; ++j)
      e[j] = uf[((size_t)b * C1 + c1 + j) * Nn + nq];
    uint4 packed;
    packed.x = pk2bf(e[0], e[1]); packed.y = pk2bf(e[2], e[3]);
    packed.z = pk2bf(e[4], e[5]); packed.w = pk2bf(e[6], e[7]);
    *(uint4*)&Fs[(((kt - 6) * NTL + ntl) * 64 + lane) * 8] = packed;
  }
#undef GATHER_KT
  __syncthreads();  // B3: F half 2 ready

  // ---- K1b: kt 6..11 reading plane kt-6
  for (int kt = 6; kt < KT1; ++kt) {
    bf16x8 Afr[4], Bfr[NTL];
#pragma unroll
    for (int r = 0; r < 4; ++r)
      Afr[r] = *(const bf16x8*)(W1f + ((size_t)(kt * RT + wv * 4 + r) * 64 + lane) * 8);
#pragma unroll
    for (int c = 0; c < NTL; ++c)
      Bfr[c] = *(const bf16x8*)&Fs[(((kt - 6) * NTL + c) * 64 + lane) * 8];
#pragma unroll
    for (int r = 0; r < 4; ++r)
#pragma unroll
      for (int c = 0; c < NTL; ++c)
        acc[r][c] = __builtin_amdgcn_mfma_f32_16x16x32_bf16(Afr[r], Bfr[c], acc[r][c], 0, 0, 0);
  }

  // ---- Epilogue 1: bias+relu in D-layout (regs only), then barrier, then
  // register bpermute D->B-frag into Hs.
#pragma unroll
  for (int r = 0; r < 4; ++r) {
    f32x4 bq = *(const f32x4*)&b1[wv * 64 + r * 16 + quad * 4];
#pragma unroll
    for (int c = 0; c < NTL; ++c)
#pragma unroll
      for (int reg = 0; reg < 4; ++reg)
        acc[r][c][reg] = fmaxf(acc[r][c][reg] + bq[reg], 0.f);
  }
  __syncthreads();  // B4: K1b's Fs reads done; Hs (overlapping region) may be written
  {
    int addr_lo = (((quad & 1) * 2) * 16 + col) * 4;  // src lane*4 for j<4
    bool hiSel = lane >= 32;
#pragma unroll
    for (int ktl = 0; ktl < 2; ++ktl)
#pragma unroll
      for (int c = 0; c < NTL; ++c) {
        float e[8];
#pragma unroll
        for (int j = 0; j < 8; ++j) {
          int addr = addr_lo + (j >> 2) * 64;
          int lo = __builtin_amdgcn_ds_bpermute(addr, __float_as_int(acc[ktl * 2][c][j & 3]));
          int hi = __builtin_amdgcn_ds_bpermute(addr, __float_as_int(acc[ktl * 2 + 1][c][j & 3]));
          e[j] = __int_as_float(hiSel ? hi : lo);
        }
        uint4 packed;
        packed.x = pk2bf(e[0], e[1]); packed.y = pk2bf(e[2], e[3]);
        packed.z = pk2bf(e[4], e[5]); packed.w = pk2bf(e[6], e[7]);
        *(uint4*)&Hs[(((wv * 2 + ktl) * NTL + c) * 64 + lane) * 8] = packed;
      }
  }
  __syncthreads();  // B5: Hs ready

  // ---- K-loop 2
  f32x4 acc2[4][NTL];
#pragma unroll
  for (int r = 0; r < 4; ++r)
#pragma unroll
    for (int c = 0; c < NTL; ++c) acc2[r][c] = (f32x4){0.f, 0.f, 0.f, 0.f};

  for (int kt = 0; kt < KT2; ++kt) {
    bf16x8 Afr[4], Bfr[NTL];
#pragma unroll
    for (int r = 0; r < 4; ++r)
      Afr[r] = *(const bf16x8*)(W2f + ((size_t)(kt * RT + wv * 4 + r) * 64 + lane) * 8);
#pragma unroll
    for (int c = 0; c < NTL; ++c)
      Bfr[c] = *(const bf16x8*)&Hs[((kt * NTL + c) * 64 + lane) * 8];
#pragma unroll
    for (int r = 0; r < 4; ++r)
#pragma unroll
      for (int c = 0; c < NTL; ++c)
        acc2[r][c] = __builtin_amdgcn_mfma_f32_16x16x32_bf16(Afr[r], Bfr[c], acc2[r][c], 0, 0, 0);
  }

  // ---- Epilogue 2: bias+relu, store
#pragma unroll
  for (int r = 0; r < 4; ++r) {
    f32x4 bq = *(const f32x4*)&b2[wv * 64 + r * 16 + quad * 4];
#pragma unroll
    for (int c = 0; c < NTL; ++c)
#pragma unroll
      for (int reg = 0; reg < 4; ++reg) {
        int rowg = wv * 64 + r * 16 + quad * 4 + reg;
        int n = bt * 32 + c * 16 + col;
        out[((size_t)b * Hh + rowg) * Nn + n] = fmaxf(acc2[r][c][reg] + bq[reg], 0.f);
      }
  }
}

extern "C" void kernel_launch(void* const* d_in, const int* in_sizes, int n_in,
                              void* d_out, int out_size, void* d_ws, size_t ws_size,
                              hipStream_t stream) {
  const float* unknown = (const float*)d_in[0];
  const float* known   = (const float*)d_in[1];
  const float* uf      = (const float*)d_in[2];
  const float* kf      = (const float*)d_in[3];
  const float* W1      = (const float*)d_in[4];
  const float* b1      = (const float*)d_in[5];
  const float* W2      = (const float*)d_in[6];
  const float* b2      = (const float*)d_in[7];
  float* out = (float*)d_out;

  // ws layout (~16 MB)
  char* p = (char*)d_ws;
  short* kfTb = (short*)p; p += (size_t)Bb * Mm * C2 * 2;   // 8.4 MB bf16
  short* W1f = (short*)p;  p += (size_t)KT1 * RT * 64 * 8 * 2;
  short* W2f = (short*)p;  p += (size_t)KT2 * RT * 64 * 8 * 2;
  float* pd  = (float*)p;  p += (size_t)Bb * Nn * NQ * 3 * 4;  // 3.1 MB
  int* pi    = (int*)p;    p += (size_t)Bb * Nn * NQ * 3 * 4;  // 3.1 MB

  const int prep_blocks = 4096 + (KT1 * RT * 64 + KT2 * RT * 64 + 255) / 256;
  prep_all_k<<<dim3(prep_blocks), dim3(256), 0, stream>>>(kf, kfTb, W1, W2, W1f, W2f);
  nn_quarter_k<<<dim3(Bb * 32 * NQ), dim3(256), 0, stream>>>(unknown, known, pd, pi);
  fused_gemm_k<<<dim3(Bb * (Nn / 32)), dim3(256), 0, stream>>>(
      uf, kfTb, W1f, b1, W2f, b2, pd, pi, out);
}

// Round 17
// 215.946 us; speedup vs baseline: 1.1558x; 1.1558x over previous
//
#include <hip/hip_runtime.h>

using bf16x8 = __attribute__((ext_vector_type(8))) short;
using f32x4  = __attribute__((ext_vector_type(4))) float;
using f32x2  = __attribute__((ext_vector_type(2))) float;

constexpr int Bb = 8, Nn = 8192, Mm = 2048, C1 = 128, C2 = 256, Hh = 256, K1 = 384;
constexpr int KT1 = K1 / 32;   // 12 k-tiles for GEMM1
constexpr int KT2 = Hh / 32;   // 8 k-tiles for GEMM2
constexpr int RT = Hh / 16;    // 16 row-tiles
constexpr int NQ = 4;          // nn: NQ=4 gated = 64.0us, best of 6 variants (R8..R14)
constexpr int MQ = Mm / NQ;    // 512 candidates per quarter

__device__ __forceinline__ short f2bf(float x) {  // RNE float->bf16
  union { float f; unsigned u; } v; v.f = x;
  unsigned r = v.u + 0x7fff + ((v.u >> 16) & 1);
  return (short)(r >> 16);
}

// packed RNE float2 -> 2x bf16 in one dword (hw instr when available)
__device__ __forceinline__ unsigned pk2bf(float a, float b) {
#if defined(__has_builtin) && __has_builtin(__builtin_amdgcn_cvt_pk_bf16_f32)
  typedef __attribute__((ext_vector_type(2))) __bf16 bf2_t;
  bf2_t r = __builtin_amdgcn_cvt_pk_bf16_f32(a, b);
  union { bf2_t v; unsigned u; } cvt; cvt.v = r;
  return cvt.u;
#else
  return (unsigned)(unsigned short)f2bf(a) | ((unsigned)(unsigned short)f2bf(b) << 16);
#endif
}

// unpack a dword holding 2 bf16 (lo = element 2i, hi = element 2i+1)
__device__ __forceinline__ float bflo(unsigned d) { return __uint_as_float(d << 16); }
__device__ __forceinline__ float bfhi(unsigned d) { return __uint_as_float(d & 0xffff0000u); }

// packed fp32 (CDNA3+). Lessons: feed ONLY from direct f32x2 loads (R9);
// two-pass recompute loses (R10); v_pk fp32 is throughput-neutral vs scalar
// (R13); 2-queries/thread loses TLP (R14). NQ=4 gated one-pass is the floor.
__device__ __forceinline__ f32x2 pk_add(f32x2 a, f32x2 b) {
  f32x2 d; asm("v_pk_add_f32 %0, %1, %2" : "=v"(d) : "v"(a), "v"(b)); return d;
}
__device__ __forceinline__ f32x2 pk_mul(f32x2 a, f32x2 b) {
  f32x2 d; asm("v_pk_mul_f32 %0, %1, %2" : "=v"(d) : "v"(a), "v"(b)); return d;
}
__device__ __forceinline__ f32x2 pk_fma(f32x2 a, f32x2 b, f32x2 c) {
  f32x2 d; asm("v_pk_fma_f32 %0, %1, %2, %3" : "=v"(d) : "v"(a), "v"(b), "v"(c)); return d;
}

// stable 2-list merge of sorted triples; ties prefer list a (lower global idx)
__device__ __forceinline__ void merge3(float a0, float a1, float a2, int A0, int A1, int A2,
                                       float b0, float b1, float b2, int B0, int B1, int B2,
                                       float& m0, float& m1, float& m2,
                                       int& j0, int& j1, int& j2) {
  bool ta = a0 <= b0;
  m0 = ta ? a0 : b0; j0 = ta ? A0 : B0;
  float na0 = ta ? a1 : a0, na1 = ta ? a2 : a1;
  int   nA0 = ta ? A1 : A0, nA1 = ta ? A2 : A1;
  float nb0 = ta ? b0 : b1, nb1 = ta ? b1 : b2;
  int   nB0 = ta ? B0 : B1, nB1 = ta ? B1 : B2;
  ta = na0 <= nb0;
  m1 = ta ? na0 : nb0; j1 = ta ? nA0 : nB0;
  float ma0 = ta ? na1 : na0; int mA0 = ta ? nA1 : nA0;
  float mb0 = ta ? nb0 : nb1; int mB0 = ta ? nB0 : nB1;
  ta = ma0 <= mb0;
  m2 = ta ? ma0 : mb0; j2 = ta ? mA0 : mB0;
}

// ------------- prep: kf transpose->bf16 (blocks 0..4095) + W frag prep -------------
// NOTE: prep, nn, fused stay SEPARATE kernels (R5/R6: fusing roles into one grid
// serialized the nn phase behind the transpose blocks, +40 us; launch overhead is
// fixed ~85 us regardless of kernel count — do not re-fuse).
__global__ __launch_bounds__(256) void prep_all_k(const float* __restrict__ kf,
                                                  short* __restrict__ kfTb,
                                                  const float* __restrict__ W1,
                                                  const float* __restrict__ W2,
                                                  short* __restrict__ W1f,
                                                  short* __restrict__ W2f) {
  __shared__ float tile[32][33];
  int bid = blockIdx.x, tid = threadIdx.x;
  if (bid < 4096) {  // transpose role: (B,C2,Mm) f32 -> (B,Mm,C2) bf16
    int cx = bid & 63, ry = (bid >> 6) & 7, z = bid >> 9;
    const float* src = kf + (size_t)z * C2 * Mm;
    short* dst = kfTb + (size_t)z * Mm * C2;
    int c0 = cx * 32, r0 = ry * 32;  // c0: point base, r0: channel base
    int tx = tid & 31, ty = tid >> 5;
#pragma unroll
    for (int rr = ty; rr < 32; rr += 8)
      tile[rr][tx] = src[(size_t)(r0 + rr) * Mm + c0 + tx];
    __syncthreads();
#pragma unroll
    for (int cc = ty; cc < 32; cc += 8)
      dst[(size_t)(c0 + cc) * C2 + r0 + tx] = f2bf(tile[tx][cc]);
    return;
  }
  // W-prep role: A-frag planes (lane holds A[m=lane&15][k0..k0+7], k0=(lane>>4)*8)
  int id = (bid - 4096) * 256 + tid;
  const int n1 = KT1 * RT * 64;
  const int n2 = KT2 * RT * 64;
  if (id < n1) {
    int lane = id & 63, t = id >> 6;
    int kt = t / RT, rt = t % RT;
    int m = rt * 16 + (lane & 15), k0 = kt * 32 + (lane >> 4) * 8;
    bf16x8 f;
#pragma unroll
    for (int j = 0; j < 8; ++j) f[j] = f2bf(W1[(size_t)m * K1 + k0 + j]);
    *(bf16x8*)(W1f + (size_t)id * 8) = f;
  } else if (id < n1 + n2) {
    int id2 = id - n1;
    int lane = id2 & 63, t = id2 >> 6;
    int kt = t / RT, rt = t % RT;
    int m = rt * 16 + (lane & 15), k0 = kt * 32 + (lane >> 4) * 8;
    bf16x8 f;
#pragma unroll
    for (int j = 0; j < 8; ++j) f[j] = f2bf(W2[(size_t)m * Hh + k0 + j]);
    *(bf16x8*)(W2f + (size_t)id2 * 8) = f;
  }
}

// ------------- three_nn over a quarter of the candidate set (R8-verbatim) -------------
// grid: b(8) x nblk(32) x q(4) = 1024 blocks of 256 -> 16 waves/CU (4/SIMD).
// Measured 64.0us (R8/R15) — best of 6 variants. Do not re-tune.
__global__ __launch_bounds__(256) void nn_quarter_k(const float* __restrict__ unknown,
                                                    const float* __restrict__ known,
                                                    float* __restrict__ pd,
                                                    int* __restrict__ pi) {
  __shared__ float kx[MQ], ky[MQ], kz[MQ];
  int bid = blockIdx.x;
  int b = bid >> 7, rem = bid & 127;
  int q = rem & 3, nblk = rem >> 2;
  int n = nblk * 256 + threadIdx.x;
  const float* kb = known + ((size_t)b * Mm + q * MQ) * 3;
  for (int p = threadIdx.x; p < MQ; p += 256) {
    kx[p] = kb[3 * p]; ky[p] = kb[3 * p + 1]; kz[p] = kb[3 * p + 2];
  }
  __syncthreads();

  size_t ui = ((size_t)b * Nn + n) * 3;
  float ux = unknown[ui], uy = unknown[ui + 1], uz = unknown[ui + 2];
  float d0 = 1e30f, d1 = 1e30f, d2 = 1e30f;
  int i0 = 0, i1 = 0, i2 = 0;
  int gbase = q * MQ;

  // broadcast negated query into packed pairs (once per thread)
  f32x2 nux = { -ux, -ux }, nuy = { -uy, -uy }, nuz = { -uz, -uz };

#define NN_INS(dd, qq)                                                  \
  {                                                                     \
    if (__any((dd) < d2)) { /* wave-uniform skip of the insert chain */ \
      int jm = gbase + jb + (qq);                                       \
      bool c0 = (dd) < d0, c1 = (dd) < d1, c2 = (dd) < d2;              \
      d2 = c1 ? d1 : (c2 ? (dd) : d2); i2 = c1 ? i1 : (c2 ? jm : i2);   \
      d1 = c0 ? d0 : (c1 ? (dd) : d1); i1 = c0 ? i0 : (c1 ? jm : i1);   \
      d0 = c0 ? (dd) : d0;             i0 = c0 ? jm : i0;               \
    }                                                                   \
  }

  const f32x2* kx2 = (const f32x2*)kx;
  const f32x2* ky2 = (const f32x2*)ky;
  const f32x2* kz2 = (const f32x2*)kz;
  for (int jb = 0; jb < MQ; jb += 4) {
    int h = jb >> 1;
    f32x2 xa = kx2[h], xb = kx2[h + 1];
    f32x2 ya = ky2[h], yb = ky2[h + 1];
    f32x2 za = kz2[h], zb = kz2[h + 1];
    // dd = (k-u)^2 summed; (k-u)^2 == (u-k)^2 bit-exact in fp32
    f32x2 dxa = pk_add(xa, nux), dya = pk_add(ya, nuy), dza = pk_add(za, nuz);
    f32x2 dda = pk_fma(dza, dza, pk_fma(dya, dya, pk_mul(dxa, dxa)));
    f32x2 dxb = pk_add(xb, nux), dyb = pk_add(yb, nuy), dzb = pk_add(zb, nuz);
    f32x2 ddb = pk_fma(dzb, dzb, pk_fma(dyb, dyb, pk_mul(dxb, dxb)));
    NN_INS(dda.x, 0)
    NN_INS(dda.y, 1)
    NN_INS(ddb.x, 2)
    NN_INS(ddb.y, 3)
  }
#undef NN_INS

  size_t o = (((size_t)b * Nn + n) * NQ + q) * 3;
  pd[o] = d0; pd[o + 1] = d1; pd[o + 2] = d2;
  pi[o] = i0; pi[o + 1] = i1; pi[o + 2] = i2;
}

// ------------- fused: 4-way merge -> gather+concat -> MLP1 -> MLP2 -> out -------------
// block = 256 thr (4 waves), 64 cols x 256 rows. grid = 8*128 = 1024 (R15 config;
// R16's 32-col split REGRESSED 62->93us: per-block serial path is width-invariant,
// fixed costs doubled — fused is critical-path-bound, not TLP-bound).
// R12 (kept): LDS 32KB — 6-plane F buffer filled twice + Hs overlay -> 4 blocks/CU.
// R17: T14 async-STAGE — phase A-2's 6 kfTb gather loads issue into REGISTERS
// right after B1 and are consumed after B2; K1a's ~96 MFMA (~480cy) hides their
// latency. +24 VGPR (~116 total, still 4 waves/SIMD). Numerics bit-identical.
__global__ __launch_bounds__(256) void fused_gemm_k(
    const float* __restrict__ uf, const short* __restrict__ kfTb,
    const short* __restrict__ W1f, const float* __restrict__ b1,
    const short* __restrict__ W2f, const float* __restrict__ b2,
    const float* __restrict__ pd, const int* __restrict__ pi,
    float* __restrict__ out) {
  __shared__ short Fs[KT2 * 4 * 64 * 8];  // 32KB: Hs region for K2; head 24KB = 6-plane F buf
  short* Hs = Fs;
  int bid = blockIdx.x;
  int b = bid >> 7, bt = bid & 127;  // n0 = bt*64
  int tid = threadIdx.x, lane = tid & 63, wv = tid >> 6;
  int quad = lane >> 4, col = lane & 15;
  const int nq = bt * 64 + wv * 16 + col;  // this thread's point

  // ---- merge: in-register 4-way NN merge (tree of 3 stable merges, R8 code).
  // Temps t-prefixed (R10 lesson: unprefixed names shadowed constexpr C1/C2).
  float w0, w1, w2;
  int g0, g1, g2;
  {
    size_t pbase = (size_t)(b * Nn + nq) * (NQ * 3);  // stride 12 floats (48B), 16B-aligned
    float4 da = *(const float4*)&pd[pbase];
    float4 db = *(const float4*)&pd[pbase + 4];
    float4 dc = *(const float4*)&pd[pbase + 8];
    int4 ia = *(const int4*)&pi[pbase];
    int4 ib = *(const int4*)&pi[pbase + 4];
    int4 ic = *(const int4*)&pi[pbase + 8];
    float t0, t1, t2, u0, u1, u2, m0, m1, m2;
    int T0, T1, T2, U0, U1, U2;
    merge3(da.x, da.y, da.z, ia.x, ia.y, ia.z,
           da.w, db.x, db.y, ia.w, ib.x, ib.y, t0, t1, t2, T0, T1, T2);
    merge3(db.z, db.w, dc.x, ib.z, ib.w, ic.x,
           dc.y, dc.z, dc.w, ic.y, ic.z, ic.w, u0, u1, u2, U0, U1, U2);
    merge3(t0, t1, t2, T0, T1, T2, u0, u1, u2, U0, U1, U2,
           m0, m1, m2, g0, g1, g2);
    float s0 = sqrtf(m0), s1 = sqrtf(m1), s2 = sqrtf(m2);
    float r0 = 1.f / (s0 + 1e-8f), r1 = 1.f / (s1 + 1e-8f), r2 = 1.f / (s2 + 1e-8f);
    float rs = 1.f / (r0 + r1 + r2);
    w0 = r0 * rs; w1 = r1 * rs; w2 = r2 * rs;
  }
  const short* kfb = kfTb + (size_t)b * Mm * C2;

  // pack 3 gathered uint4 rows with interpolation weights into one B-frag store
#define PACK_STORE(q0, q1, q2, plane)                                         \
  {                                                                           \
    float e0 = w0 * bflo((q0).x) + w1 * bflo((q1).x) + w2 * bflo((q2).x);     \
    float e1 = w0 * bfhi((q0).x) + w1 * bfhi((q1).x) + w2 * bfhi((q2).x);     \
    float e2 = w0 * bflo((q0).y) + w1 * bflo((q1).y) + w2 * bflo((q2).y);     \
    float e3 = w0 * bfhi((q0).y) + w1 * bfhi((q1).y) + w2 * bfhi((q2).y);     \
    float e4 = w0 * bflo((q0).z) + w1 * bflo((q1).z) + w2 * bflo((q2).z);     \
    float e5 = w0 * bfhi((q0).z) + w1 * bfhi((q1).z) + w2 * bfhi((q2).z);     \
    float e6 = w0 * bflo((q0).w) + w1 * bflo((q1).w) + w2 * bflo((q2).w);     \
    float e7 = w0 * bfhi((q0).w) + w1 * bfhi((q1).w) + w2 * bfhi((q2).w);     \
    uint4 packed;                                                             \
    packed.x = pk2bf(e0, e1); packed.y = pk2bf(e2, e3);                       \
    packed.z = pk2bf(e4, e5); packed.w = pk2bf(e6, e7);                       \
    *(uint4*)&Fs[(((plane) * 4 + wv) * 64 + lane) * 8] = packed;              \
  }

#define GATHER_KT(kt, plane)                                                  \
  {                                                                           \
    int c0 = (kt) * 32 + quad * 8;                                            \
    uint4 q0 = *(const uint4*)&kfb[(size_t)g0 * C2 + c0];                     \
    uint4 q1 = *(const uint4*)&kfb[(size_t)g1 * C2 + c0];                     \
    uint4 q2 = *(const uint4*)&kfb[(size_t)g2 * C2 + c0];                     \
    PACK_STORE(q0, q1, q2, plane)                                             \
  }

  // ---- Phase A-1: gather kt 0..5 into planes 0..5
#pragma unroll 3
  for (int kt = 0; kt < 6; ++kt) GATHER_KT(kt, kt)
  __syncthreads();  // B1: F half 1 ready

  // ---- T14 prefetch: issue phase A-2's kt 6,7 gather loads NOW (consumed
  // after B2). K1a's MFMA stream hides their ~500cy latency.
  uint4 pf0, pf1, pf2, pf3, pf4, pf5;
  {
    int c06 = 6 * 32 + quad * 8, c07 = 7 * 32 + quad * 8;
    pf0 = *(const uint4*)&kfb[(size_t)g0 * C2 + c06];
    pf1 = *(const uint4*)&kfb[(size_t)g1 * C2 + c06];
    pf2 = *(const uint4*)&kfb[(size_t)g2 * C2 + c06];
    pf3 = *(const uint4*)&kfb[(size_t)g0 * C2 + c07];
    pf4 = *(const uint4*)&kfb[(size_t)g1 * C2 + c07];
    pf5 = *(const uint4*)&kfb[(size_t)g2 * C2 + c07];
  }

  // ---- K1a: kt 0..5
  f32x4 acc[4][4];
#pragma unroll
  for (int r = 0; r < 4; ++r)
#pragma unroll
    for (int c = 0; c < 4; ++c) acc[r][c] = (f32x4){0.f, 0.f, 0.f, 0.f};

  for (int kt = 0; kt < 6; ++kt) {
    bf16x8 Afr[4], Bfr[4];
#pragma unroll
    for (int r = 0; r < 4; ++r)
      Afr[r] = *(const bf16x8*)(W1f + ((size_t)(kt * RT + wv * 4 + r) * 64 + lane) * 8);
#pragma unroll
    for (int c = 0; c < 4; ++c)
      Bfr[c] = *(const bf16x8*)&Fs[((kt * 4 + c) * 64 + lane) * 8];
#pragma unroll
    for (int r = 0; r < 4; ++r)
#pragma unroll
      for (int c = 0; c < 4; ++c)
        acc[r][c] = __builtin_amdgcn_mfma_f32_16x16x32_bf16(Afr[r], Bfr[c], acc[r][c], 0, 0, 0);
  }
  __syncthreads();  // B2: half-1 reads done; planes reusable

  // ---- Phase A-2: consume prefetched kt 6,7; load uf kt 8..11 (coalesced)
  PACK_STORE(pf0, pf1, pf2, 0)
  PACK_STORE(pf3, pf4, pf5, 1)
#pragma unroll 2
  for (int kt = 8; kt < 12; ++kt) {  // unknow_feats region (C1 channels)
    int c1 = (kt - 8) * 32 + quad * 8;
    float e[8];
#pragma unroll
    for (int j = 0; j < 8; ++j)
      e[j] = uf[((size_t)b * C1 + c1 + j) * Nn + nq];
    uint4 packed;
    packed.x = pk2bf(e[0], e[1]); packed.y = pk2bf(e[2], e[3]);
    packed.z = pk2bf(e[4], e[5]); packed.w = pk2bf(e[6], e[7]);
    *(uint4*)&Fs[(((kt - 6) * 4 + wv) * 64 + lane) * 8] = packed;
  }
#undef GATHER_KT
#undef PACK_STORE
  __syncthreads();  // B3: F half 2 ready

  // ---- K1b: kt 6..11 reading plane kt-6
  for (int kt = 6; kt < KT1; ++kt) {
    bf16x8 Afr[4], Bfr[4];
#pragma unroll
    for (int r = 0; r < 4; ++r)
      Afr[r] = *(const bf16x8*)(W1f + ((size_t)(kt * RT + wv * 4 + r) * 64 + lane) * 8);
#pragma unroll
    for (int c = 0; c < 4; ++c)
      Bfr[c] = *(const bf16x8*)&Fs[(((kt - 6) * 4 + c) * 64 + lane) * 8];
#pragma unroll
    for (int r = 0; r < 4; ++r)
#pragma unroll
      for (int c = 0; c < 4; ++c)
        acc[r][c] = __builtin_amdgcn_mfma_f32_16x16x32_bf16(Afr[r], Bfr[c], acc[r][c], 0, 0, 0);
  }

  // ---- Epilogue 1: bias+relu in D-layout (regs only), then barrier, then
  // register bpermute D->B-frag into Hs.
#pragma unroll
  for (int r = 0; r < 4; ++r) {
    f32x4 bq = *(const f32x4*)&b1[wv * 64 + r * 16 + quad * 4];
#pragma unroll
    for (int c = 0; c < 4; ++c)
#pragma unroll
      for (int reg = 0; reg < 4; ++reg)
        acc[r][c][reg] = fmaxf(acc[r][c][reg] + bq[reg], 0.f);
  }
  __syncthreads();  // B4: K1b's Fs reads done; Hs (overlapping region) may be written
  {
    int addr_lo = (((quad & 1) * 2) * 16 + col) * 4;  // src lane*4 for j<4
    bool hiSel = lane >= 32;
#pragma unroll
    for (int ktl = 0; ktl < 2; ++ktl)
#pragma unroll
      for (int c = 0; c < 4; ++c) {
        float e[8];
#pragma unroll
        for (int j = 0; j < 8; ++j) {
          int addr = addr_lo + (j >> 2) * 64;
          int lo = __builtin_amdgcn_ds_bpermute(addr, __float_as_int(acc[ktl * 2][c][j & 3]));
          int hi = __builtin_amdgcn_ds_bpermute(addr, __float_as_int(acc[ktl * 2 + 1][c][j & 3]));
          e[j] = __int_as_float(hiSel ? hi : lo);
        }
        uint4 packed;
        packed.x = pk2bf(e[0], e[1]); packed.y = pk2bf(e[2], e[3]);
        packed.z = pk2bf(e[4], e[5]); packed.w = pk2bf(e[6], e[7]);
        *(uint4*)&Hs[(((wv * 2 + ktl) * 4 + c) * 64 + lane) * 8] = packed;
      }
  }
  __syncthreads();  // B5: Hs ready

  // ---- K-loop 2
  f32x4 acc2[4][4];
#pragma unroll
  for (int r = 0; r < 4; ++r)
#pragma unroll
    for (int c = 0; c < 4; ++c) acc2[r][c] = (f32x4){0.f, 0.f, 0.f, 0.f};

  for (int kt = 0; kt < KT2; ++kt) {
    bf16x8 Afr[4], Bfr[4];
#pragma unroll
    for (int r = 0; r < 4; ++r)
      Afr[r] = *(const bf16x8*)(W2f + ((size_t)(kt * RT + wv * 4 + r) * 64 + lane) * 8);
#pragma unroll
    for (int c = 0; c < 4; ++c)
      Bfr[c] = *(const bf16x8*)&Hs[((kt * 4 + c) * 64 + lane) * 8];
#pragma unroll
    for (int r = 0; r < 4; ++r)
#pragma unroll
      for (int c = 0; c < 4; ++c)
        acc2[r][c] = __builtin_amdgcn_mfma_f32_16x16x32_bf16(Afr[r], Bfr[c], acc2[r][c], 0, 0, 0);
  }

  // ---- Epilogue 2: bias+relu, store
#pragma unroll
  for (int r = 0; r < 4; ++r) {
    f32x4 bq = *(const f32x4*)&b2[wv * 64 + r * 16 + quad * 4];
#pragma unroll
    for (int c = 0; c < 4; ++c)
#pragma unroll
      for (int reg = 0; reg < 4; ++reg) {
        int rowg = wv * 64 + r * 16 + quad * 4 + reg;
        int n = bt * 64 + c * 16 + col;
        out[((size_t)b * Hh + rowg) * Nn + n] = fmaxf(acc2[r][c][reg] + bq[reg], 0.f);
      }
  }
}

extern "C" void kernel_launch(void* const* d_in, const int* in_sizes, int n_in,
                              void* d_out, int out_size, void* d_ws, size_t ws_size,
                              hipStream_t stream) {
  const float* unknown = (const float*)d_in[0];
  const float* known   = (const float*)d_in[1];
  const float* uf      = (const float*)d_in[2];
  const float* kf      = (const float*)d_in[3];
  const float* W1      = (const float*)d_in[4];
  const float* b1      = (const float*)d_in[5];
  const float* W2      = (const float*)d_in[6];
  const float* b2      = (const float*)d_in[7];
  float* out = (float*)d_out;

  // ws layout (~16 MB)
  char* p = (char*)d_ws;
  short* kfTb = (short*)p; p += (size_t)Bb * Mm * C2 * 2;   // 8.4 MB bf16
  short* W1f = (short*)p;  p += (size_t)KT1 * RT * 64 * 8 * 2;
  short* W2f = (short*)p;  p += (size_t)KT2 * RT * 64 * 8 * 2;
  float* pd  = (float*)p;  p += (size_t)Bb * Nn * NQ * 3 * 4;  // 3.1 MB
  int* pi    = (int*)p;    p += (size_t)Bb * Nn * NQ * 3 * 4;  // 3.1 MB

  const int prep_blocks = 4096 + (KT1 * RT * 64 + KT2 * RT * 64 + 255) / 256;
  prep_all_k<<<dim3(prep_blocks), dim3(256), 0, stream>>>(kf, kfTb, W1, W2, W1f, W2f);
  nn_quarter_k<<<dim3(Bb * 32 * NQ), dim3(256), 0, stream>>>(unknown, known, pd, pi);
  fused_gemm_k<<<dim3(Bb * (Nn / 64)), dim3(256), 0, stream>>>(
      uf, kfTb, W1f, b1, W2f, b2, pd, pi, out);
}

// Round 18
// 214.768 us; speedup vs baseline: 1.1621x; 1.0055x over previous
//
#include <hip/hip_runtime.h>

using bf16x8 = __attribute__((ext_vector_type(8))) short;
using f32x4  = __attribute__((ext_vector_type(4))) float;
using f32x2  = __attribute__((ext_vector_type(2))) float;

constexpr int Bb = 8, Nn = 8192, Mm = 2048, C1 = 128, C2 = 256, Hh = 256, K1 = 384;
constexpr int KT1 = K1 / 32;   // 12 k-tiles for GEMM1
constexpr int KT2 = Hh / 32;   // 8 k-tiles for GEMM2
constexpr int RT = Hh / 16;    // 16 row-tiles
constexpr int NQ = 4;          // nn: NQ=4 gated = 64.0us, best of 6 variants (R8..R14)
constexpr int MQ = Mm / NQ;    // 512 candidates per quarter

__device__ __forceinline__ short f2bf(float x) {  // RNE float->bf16
  union { float f; unsigned u; } v; v.f = x;
  unsigned r = v.u + 0x7fff + ((v.u >> 16) & 1);
  return (short)(r >> 16);
}

// packed RNE float2 -> 2x bf16 in one dword (hw instr when available)
__device__ __forceinline__ unsigned pk2bf(float a, float b) {
#if defined(__has_builtin) && __has_builtin(__builtin_amdgcn_cvt_pk_bf16_f32)
  typedef __attribute__((ext_vector_type(2))) __bf16 bf2_t;
  bf2_t r = __builtin_amdgcn_cvt_pk_bf16_f32(a, b);
  union { bf2_t v; unsigned u; } cvt; cvt.v = r;
  return cvt.u;
#else
  return (unsigned)(unsigned short)f2bf(a) | ((unsigned)(unsigned short)f2bf(b) << 16);
#endif
}

// unpack a dword holding 2 bf16 (lo = element 2i, hi = element 2i+1)
__device__ __forceinline__ float bflo(unsigned d) { return __uint_as_float(d << 16); }
__device__ __forceinline__ float bfhi(unsigned d) { return __uint_as_float(d & 0xffff0000u); }

// packed fp32 (CDNA3+). Lessons: feed ONLY from direct f32x2 loads (R9);
// two-pass recompute loses (R10); v_pk fp32 is throughput-neutral vs scalar
// (R13); 2-queries/thread loses TLP (R14). NQ=4 gated one-pass is the floor.
__device__ __forceinline__ f32x2 pk_add(f32x2 a, f32x2 b) {
  f32x2 d; asm("v_pk_add_f32 %0, %1, %2" : "=v"(d) : "v"(a), "v"(b)); return d;
}
__device__ __forceinline__ f32x2 pk_mul(f32x2 a, f32x2 b) {
  f32x2 d; asm("v_pk_mul_f32 %0, %1, %2" : "=v"(d) : "v"(a), "v"(b)); return d;
}
__device__ __forceinline__ f32x2 pk_fma(f32x2 a, f32x2 b, f32x2 c) {
  f32x2 d; asm("v_pk_fma_f32 %0, %1, %2, %3" : "=v"(d) : "v"(a), "v"(b), "v"(c)); return d;
}

// stable 2-list merge of sorted triples; ties prefer list a (lower global idx)
__device__ __forceinline__ void merge3(float a0, float a1, float a2, int A0, int A1, int A2,
                                       float b0, float b1, float b2, int B0, int B1, int B2,
                                       float& m0, float& m1, float& m2,
                                       int& j0, int& j1, int& j2) {
  bool ta = a0 <= b0;
  m0 = ta ? a0 : b0; j0 = ta ? A0 : B0;
  float na0 = ta ? a1 : a0, na1 = ta ? a2 : a1;
  int   nA0 = ta ? A1 : A0, nA1 = ta ? A2 : A1;
  float nb0 = ta ? b0 : b1, nb1 = ta ? b1 : b2;
  int   nB0 = ta ? B0 : B1, nB1 = ta ? B1 : B2;
  ta = na0 <= nb0;
  m1 = ta ? na0 : nb0; j1 = ta ? nA0 : nB0;
  float ma0 = ta ? na1 : na0; int mA0 = ta ? nA1 : nA0;
  float mb0 = ta ? nb0 : nb1; int mB0 = ta ? nB0 : nB1;
  ta = ma0 <= mb0;
  m2 = ta ? ma0 : mb0; j2 = ta ? mA0 : mB0;
}

// ------------- prep: kf transpose->bf16 (blocks 0..4095) + W frag prep -------------
// NOTE: prep, nn, fused stay SEPARATE kernels (R5/R6: fusing roles into one grid
// serialized the nn phase behind the transpose blocks, +40 us; launch overhead is
// fixed ~85 us regardless of kernel count — do not re-fuse).
__global__ __launch_bounds__(256) void prep_all_k(const float* __restrict__ kf,
                                                  short* __restrict__ kfTb,
                                                  const float* __restrict__ W1,
                                                  const float* __restrict__ W2,
                                                  short* __restrict__ W1f,
                                                  short* __restrict__ W2f) {
  __shared__ float tile[32][33];
  int bid = blockIdx.x, tid = threadIdx.x;
  if (bid < 4096) {  // transpose role: (B,C2,Mm) f32 -> (B,Mm,C2) bf16
    int cx = bid & 63, ry = (bid >> 6) & 7, z = bid >> 9;
    const float* src = kf + (size_t)z * C2 * Mm;
    short* dst = kfTb + (size_t)z * Mm * C2;
    int c0 = cx * 32, r0 = ry * 32;  // c0: point base, r0: channel base
    int tx = tid & 31, ty = tid >> 5;
#pragma unroll
    for (int rr = ty; rr < 32; rr += 8)
      tile[rr][tx] = src[(size_t)(r0 + rr) * Mm + c0 + tx];
    __syncthreads();
#pragma unroll
    for (int cc = ty; cc < 32; cc += 8)
      dst[(size_t)(c0 + cc) * C2 + r0 + tx] = f2bf(tile[tx][cc]);
    return;
  }
  // W-prep role: A-frag planes (lane holds A[m=lane&15][k0..k0+7], k0=(lane>>4)*8)
  int id = (bid - 4096) * 256 + tid;
  const int n1 = KT1 * RT * 64;
  const int n2 = KT2 * RT * 64;
  if (id < n1) {
    int lane = id & 63, t = id >> 6;
    int kt = t / RT, rt = t % RT;
    int m = rt * 16 + (lane & 15), k0 = kt * 32 + (lane >> 4) * 8;
    bf16x8 f;
#pragma unroll
    for (int j = 0; j < 8; ++j) f[j] = f2bf(W1[(size_t)m * K1 + k0 + j]);
    *(bf16x8*)(W1f + (size_t)id * 8) = f;
  } else if (id < n1 + n2) {
    int id2 = id - n1;
    int lane = id2 & 63, t = id2 >> 6;
    int kt = t / RT, rt = t % RT;
    int m = rt * 16 + (lane & 15), k0 = kt * 32 + (lane >> 4) * 8;
    bf16x8 f;
#pragma unroll
    for (int j = 0; j < 8; ++j) f[j] = f2bf(W2[(size_t)m * Hh + k0 + j]);
    *(bf16x8*)(W2f + (size_t)id2 * 8) = f;
  }
}

// ------------- three_nn over a quarter of the candidate set (R8-verbatim) -------------
// grid: b(8) x nblk(32) x q(4) = 1024 blocks of 256 -> 16 waves/CU (4/SIMD).
// Measured 64.0us (R8/R15/R17) — best of 6 variants. Do not re-tune.
__global__ __launch_bounds__(256) void nn_quarter_k(const float* __restrict__ unknown,
                                                    const float* __restrict__ known,
                                                    float* __restrict__ pd,
                                                    int* __restrict__ pi) {
  __shared__ float kx[MQ], ky[MQ], kz[MQ];
  int bid = blockIdx.x;
  int b = bid >> 7, rem = bid & 127;
  int q = rem & 3, nblk = rem >> 2;
  int n = nblk * 256 + threadIdx.x;
  const float* kb = known + ((size_t)b * Mm + q * MQ) * 3;
  for (int p = threadIdx.x; p < MQ; p += 256) {
    kx[p] = kb[3 * p]; ky[p] = kb[3 * p + 1]; kz[p] = kb[3 * p + 2];
  }
  __syncthreads();

  size_t ui = ((size_t)b * Nn + n) * 3;
  float ux = unknown[ui], uy = unknown[ui + 1], uz = unknown[ui + 2];
  float d0 = 1e30f, d1 = 1e30f, d2 = 1e30f;
  int i0 = 0, i1 = 0, i2 = 0;
  int gbase = q * MQ;

  // broadcast negated query into packed pairs (once per thread)
  f32x2 nux = { -ux, -ux }, nuy = { -uy, -uy }, nuz = { -uz, -uz };

#define NN_INS(dd, qq)                                                  \
  {                                                                     \
    if (__any((dd) < d2)) { /* wave-uniform skip of the insert chain */ \
      int jm = gbase + jb + (qq);                                       \
      bool c0 = (dd) < d0, c1 = (dd) < d1, c2 = (dd) < d2;              \
      d2 = c1 ? d1 : (c2 ? (dd) : d2); i2 = c1 ? i1 : (c2 ? jm : i2);   \
      d1 = c0 ? d0 : (c1 ? (dd) : d1); i1 = c0 ? i0 : (c1 ? jm : i1);   \
      d0 = c0 ? (dd) : d0;             i0 = c0 ? jm : i0;               \
    }                                                                   \
  }

  const f32x2* kx2 = (const f32x2*)kx;
  const f32x2* ky2 = (const f32x2*)ky;
  const f32x2* kz2 = (const f32x2*)kz;
  for (int jb = 0; jb < MQ; jb += 4) {
    int h = jb >> 1;
    f32x2 xa = kx2[h], xb = kx2[h + 1];
    f32x2 ya = ky2[h], yb = ky2[h + 1];
    f32x2 za = kz2[h], zb = kz2[h + 1];
    // dd = (k-u)^2 summed; (k-u)^2 == (u-k)^2 bit-exact in fp32
    f32x2 dxa = pk_add(xa, nux), dya = pk_add(ya, nuy), dza = pk_add(za, nuz);
    f32x2 dda = pk_fma(dza, dza, pk_fma(dya, dya, pk_mul(dxa, dxa)));
    f32x2 dxb = pk_add(xb, nux), dyb = pk_add(yb, nuy), dzb = pk_add(zb, nuz);
    f32x2 ddb = pk_fma(dzb, dzb, pk_fma(dyb, dyb, pk_mul(dxb, dxb)));
    NN_INS(dda.x, 0)
    NN_INS(dda.y, 1)
    NN_INS(ddb.x, 2)
    NN_INS(ddb.y, 3)
  }
#undef NN_INS

  size_t o = (((size_t)b * Nn + n) * NQ + q) * 3;
  pd[o] = d0; pd[o + 1] = d1; pd[o + 2] = d2;
  pi[o] = i0; pi[o + 1] = i1; pi[o + 2] = i2;
}

// ------------- fused: 4-way merge -> gather+concat -> MLP1 -> MLP2 -> out -------------
// block = 256 thr (4 waves), 64 cols x 256 rows. grid = 8*128 = 1024 (R15 config;
// R16's 32-col split REGRESSED 62->93us: per-block serial path is width-invariant —
// fused is critical-path-bound, not TLP-bound).
// R12 (kept): LDS 32KB — 6-plane F buffer filled twice + Hs overlay -> 4 blocks/CU.
// R17 (kept): T14 prefetch of kt6/7 gather into regs after B1 (hidden under K1a).
// R18: A-2 reorder — issue all 32 uf loads FIRST, then the 2 PACK_STOREs (~120
// VALU) cover their latency, then pack uf. All indices unrolled-constant (no
// scratch). Risk: peak VGPR >128 -> 3 waves/SIMD (watch VGPR counter).
__global__ __launch_bounds__(256) void fused_gemm_k(
    const float* __restrict__ uf, const short* __restrict__ kfTb,
    const short* __restrict__ W1f, const float* __restrict__ b1,
    const short* __restrict__ W2f, const float* __restrict__ b2,
    const float* __restrict__ pd, const int* __restrict__ pi,
    float* __restrict__ out) {
  __shared__ short Fs[KT2 * 4 * 64 * 8];  // 32KB: Hs region for K2; head 24KB = 6-plane F buf
  short* Hs = Fs;
  int bid = blockIdx.x;
  int b = bid >> 7, bt = bid & 127;  // n0 = bt*64
  int tid = threadIdx.x, lane = tid & 63, wv = tid >> 6;
  int quad = lane >> 4, col = lane & 15;
  const int nq = bt * 64 + wv * 16 + col;  // this thread's point

  // ---- merge: in-register 4-way NN merge (tree of 3 stable merges, R8 code).
  // Temps t-prefixed (R10 lesson: unprefixed names shadowed constexpr C1/C2).
  float w0, w1, w2;
  int g0, g1, g2;
  {
    size_t pbase = (size_t)(b * Nn + nq) * (NQ * 3);  // stride 12 floats (48B), 16B-aligned
    float4 da = *(const float4*)&pd[pbase];
    float4 db = *(const float4*)&pd[pbase + 4];
    float4 dc = *(const float4*)&pd[pbase + 8];
    int4 ia = *(const int4*)&pi[pbase];
    int4 ib = *(const int4*)&pi[pbase + 4];
    int4 ic = *(const int4*)&pi[pbase + 8];
    float t0, t1, t2, u0, u1, u2, m0, m1, m2;
    int T0, T1, T2, U0, U1, U2;
    merge3(da.x, da.y, da.z, ia.x, ia.y, ia.z,
           da.w, db.x, db.y, ia.w, ib.x, ib.y, t0, t1, t2, T0, T1, T2);
    merge3(db.z, db.w, dc.x, ib.z, ib.w, ic.x,
           dc.y, dc.z, dc.w, ic.y, ic.z, ic.w, u0, u1, u2, U0, U1, U2);
    merge3(t0, t1, t2, T0, T1, T2, u0, u1, u2, U0, U1, U2,
           m0, m1, m2, g0, g1, g2);
    float s0 = sqrtf(m0), s1 = sqrtf(m1), s2 = sqrtf(m2);
    float r0 = 1.f / (s0 + 1e-8f), r1 = 1.f / (s1 + 1e-8f), r2 = 1.f / (s2 + 1e-8f);
    float rs = 1.f / (r0 + r1 + r2);
    w0 = r0 * rs; w1 = r1 * rs; w2 = r2 * rs;
  }
  const short* kfb = kfTb + (size_t)b * Mm * C2;

  // pack 3 gathered uint4 rows with interpolation weights into one B-frag store
#define PACK_STORE(q0, q1, q2, plane)                                         \
  {                                                                           \
    float e0 = w0 * bflo((q0).x) + w1 * bflo((q1).x) + w2 * bflo((q2).x);     \
    float e1 = w0 * bfhi((q0).x) + w1 * bfhi((q1).x) + w2 * bfhi((q2).x);     \
    float e2 = w0 * bflo((q0).y) + w1 * bflo((q1).y) + w2 * bflo((q2).y);     \
    float e3 = w0 * bfhi((q0).y) + w1 * bfhi((q1).y) + w2 * bfhi((q2).y);     \
    float e4 = w0 * bflo((q0).z) + w1 * bflo((q1).z) + w2 * bflo((q2).z);     \
    float e5 = w0 * bfhi((q0).z) + w1 * bfhi((q1).z) + w2 * bfhi((q2).z);     \
    float e6 = w0 * bflo((q0).w) + w1 * bflo((q1).w) + w2 * bflo((q2).w);     \
    float e7 = w0 * bfhi((q0).w) + w1 * bfhi((q1).w) + w2 * bfhi((q2).w);     \
    uint4 packed;                                                             \
    packed.x = pk2bf(e0, e1); packed.y = pk2bf(e2, e3);                       \
    packed.z = pk2bf(e4, e5); packed.w = pk2bf(e6, e7);                       \
    *(uint4*)&Fs[(((plane) * 4 + wv) * 64 + lane) * 8] = packed;              \
  }

#define GATHER_KT(kt, plane)                                                  \
  {                                                                           \
    int c0 = (kt) * 32 + quad * 8;                                            \
    uint4 q0 = *(const uint4*)&kfb[(size_t)g0 * C2 + c0];                     \
    uint4 q1 = *(const uint4*)&kfb[(size_t)g1 * C2 + c0];                     \
    uint4 q2 = *(const uint4*)&kfb[(size_t)g2 * C2 + c0];                     \
    PACK_STORE(q0, q1, q2, plane)                                             \
  }

  // ---- Phase A-1: gather kt 0..5 into planes 0..5
#pragma unroll 3
  for (int kt = 0; kt < 6; ++kt) GATHER_KT(kt, kt)
  __syncthreads();  // B1: F half 1 ready

  // ---- T14 prefetch: issue phase A-2's kt 6,7 gather loads NOW (consumed
  // after B2). K1a's MFMA stream hides their ~500cy latency.
  uint4 pf0, pf1, pf2, pf3, pf4, pf5;
  {
    int c06 = 6 * 32 + quad * 8, c07 = 7 * 32 + quad * 8;
    pf0 = *(const uint4*)&kfb[(size_t)g0 * C2 + c06];
    pf1 = *(const uint4*)&kfb[(size_t)g1 * C2 + c06];
    pf2 = *(const uint4*)&kfb[(size_t)g2 * C2 + c06];
    pf3 = *(const uint4*)&kfb[(size_t)g0 * C2 + c07];
    pf4 = *(const uint4*)&kfb[(size_t)g1 * C2 + c07];
    pf5 = *(const uint4*)&kfb[(size_t)g2 * C2 + c07];
  }

  // ---- K1a: kt 0..5
  f32x4 acc[4][4];
#pragma unroll
  for (int r = 0; r < 4; ++r)
#pragma unroll
    for (int c = 0; c < 4; ++c) acc[r][c] = (f32x4){0.f, 0.f, 0.f, 0.f};

  for (int kt = 0; kt < 6; ++kt) {
    bf16x8 Afr[4], Bfr[4];
#pragma unroll
    for (int r = 0; r < 4; ++r)
      Afr[r] = *(const bf16x8*)(W1f + ((size_t)(kt * RT + wv * 4 + r) * 64 + lane) * 8);
#pragma unroll
    for (int c = 0; c < 4; ++c)
      Bfr[c] = *(const bf16x8*)&Fs[((kt * 4 + c) * 64 + lane) * 8];
#pragma unroll
    for (int r = 0; r < 4; ++r)
#pragma unroll
      for (int c = 0; c < 4; ++c)
        acc[r][c] = __builtin_amdgcn_mfma_f32_16x16x32_bf16(Afr[r], Bfr[c], acc[r][c], 0, 0, 0);
  }
  __syncthreads();  // B2: half-1 reads done; planes reusable

  // ---- Phase A-2 (R18 order): (1) issue all uf loads, (2) pack prefetched
  // kt6/7 while loads fly, (3) pack uf. Indices unrolled-constant -> registers.
  float eu[4][8];
#pragma unroll
  for (int kt = 8; kt < 12; ++kt) {
    int c1 = (kt - 8) * 32 + quad * 8;
#pragma unroll
    for (int j = 0; j < 8; ++j)
      eu[kt - 8][j] = uf[((size_t)b * C1 + c1 + j) * Nn + nq];
  }
  PACK_STORE(pf0, pf1, pf2, 0)
  PACK_STORE(pf3, pf4, pf5, 1)
#pragma unroll
  for (int kt = 8; kt < 12; ++kt) {
    uint4 packed;
    packed.x = pk2bf(eu[kt - 8][0], eu[kt - 8][1]);
    packed.y = pk2bf(eu[kt - 8][2], eu[kt - 8][3]);
    packed.z = pk2bf(eu[kt - 8][4], eu[kt - 8][5]);
    packed.w = pk2bf(eu[kt - 8][6], eu[kt - 8][7]);
    *(uint4*)&Fs[(((kt - 6) * 4 + wv) * 64 + lane) * 8] = packed;
  }
#undef GATHER_KT
#undef PACK_STORE
  __syncthreads();  // B3: F half 2 ready

  // ---- K1b: kt 6..11 reading plane kt-6
  for (int kt = 6; kt < KT1; ++kt) {
    bf16x8 Afr[4], Bfr[4];
#pragma unroll
    for (int r = 0; r < 4; ++r)
      Afr[r] = *(const bf16x8*)(W1f + ((size_t)(kt * RT + wv * 4 + r) * 64 + lane) * 8);
#pragma unroll
    for (int c = 0; c < 4; ++c)
      Bfr[c] = *(const bf16x8*)&Fs[(((kt - 6) * 4 + c) * 64 + lane) * 8];
#pragma unroll
    for (int r = 0; r < 4; ++r)
#pragma unroll
      for (int c = 0; c < 4; ++c)
        acc[r][c] = __builtin_amdgcn_mfma_f32_16x16x32_bf16(Afr[r], Bfr[c], acc[r][c], 0, 0, 0);
  }

  // ---- Epilogue 1: bias+relu in D-layout (regs only), then barrier, then
  // register bpermute D->B-frag into Hs.
#pragma unroll
  for (int r = 0; r < 4; ++r) {
    f32x4 bq = *(const f32x4*)&b1[wv * 64 + r * 16 + quad * 4];
#pragma unroll
    for (int c = 0; c < 4; ++c)
#pragma unroll
      for (int reg = 0; reg < 4; ++reg)
        acc[r][c][reg] = fmaxf(acc[r][c][reg] + bq[reg], 0.f);
  }
  __syncthreads();  // B4: K1b's Fs reads done; Hs (overlapping region) may be written
  {
    int addr_lo = (((quad & 1) * 2) * 16 + col) * 4;  // src lane*4 for j<4
    bool hiSel = lane >= 32;
#pragma unroll
    for (int ktl = 0; ktl < 2; ++ktl)
#pragma unroll
      for (int c = 0; c < 4; ++c) {
        float e[8];
#pragma unroll
        for (int j = 0; j < 8; ++j) {
          int addr = addr_lo + (j >> 2) * 64;
          int lo = __builtin_amdgcn_ds_bpermute(addr, __float_as_int(acc[ktl * 2][c][j & 3]));
          int hi = __builtin_amdgcn_ds_bpermute(addr, __float_as_int(acc[ktl * 2 + 1][c][j & 3]));
          e[j] = __int_as_float(hiSel ? hi : lo);
        }
        uint4 packed;
        packed.x = pk2bf(e[0], e[1]); packed.y = pk2bf(e[2], e[3]);
        packed.z = pk2bf(e[4], e[5]); packed.w = pk2bf(e[6], e[7]);
        *(uint4*)&Hs[(((wv * 2 + ktl) * 4 + c) * 64 + lane) * 8] = packed;
      }
  }
  __syncthreads();  // B5: Hs ready

  // ---- K-loop 2
  f32x4 acc2[4][4];
#pragma unroll
  for (int r = 0; r < 4; ++r)
#pragma unroll
    for (int c = 0; c < 4; ++c) acc2[r][c] = (f32x4){0.f, 0.f, 0.f, 0.f};

  for (int kt = 0; kt < KT2; ++kt) {
    bf16x8 Afr[4], Bfr[4];
#pragma unroll
    for (int r = 0; r < 4; ++r)
      Afr[r] = *(const bf16x8*)(W2f + ((size_t)(kt * RT + wv * 4 + r) * 64 + lane) * 8);
#pragma unroll
    for (int c = 0; c < 4; ++c)
      Bfr[c] = *(const bf16x8*)&Hs[((kt * 4 + c) * 64 + lane) * 8];
#pragma unroll
    for (int r = 0; r < 4; ++r)
#pragma unroll
      for (int c = 0; c < 4; ++c)
        acc2[r][c] = __builtin_amdgcn_mfma_f32_16x16x32_bf16(Afr[r], Bfr[c], acc2[r][c], 0, 0, 0);
  }

  // ---- Epilogue 2: bias+relu, store
#pragma unroll
  for (int r = 0; r < 4; ++r) {
    f32x4 bq = *(const f32x4*)&b2[wv * 64 + r * 16 + quad * 4];
#pragma unroll
    for (int c = 0; c < 4; ++c)
#pragma unroll
      for (int reg = 0; reg < 4; ++reg) {
        int rowg = wv * 64 + r * 16 + quad * 4 + reg;
        int n = bt * 64 + c * 16 + col;
        out[((size_t)b * Hh + rowg) * Nn + n] = fmaxf(acc2[r][c][reg] + bq[reg], 0.f);
      }
  }
}

extern "C" void kernel_launch(void* const* d_in, const int* in_sizes, int n_in,
                              void* d_out, int out_size, void* d_ws, size_t ws_size,
                              hipStream_t stream) {
  const float* unknown = (const float*)d_in[0];
  const float* known   = (const float*)d_in[1];
  const float* uf      = (const float*)d_in[2];
  const float* kf      = (const float*)d_in[3];
  const float* W1      = (const float*)d_in[4];
  const float* b1      = (const float*)d_in[5];
  const float* W2      = (const float*)d_in[6];
  const float* b2      = (const float*)d_in[7];
  float* out = (float*)d_out;

  // ws layout (~16 MB)
  char* p = (char*)d_ws;
  short* kfTb = (short*)p; p += (size_t)Bb * Mm * C2 * 2;   // 8.4 MB bf16
  short* W1f = (short*)p;  p += (size_t)KT1 * RT * 64 * 8 * 2;
  short* W2f = (short*)p;  p += (size_t)KT2 * RT * 64 * 8 * 2;
  float* pd  = (float*)p;  p += (size_t)Bb * Nn * NQ * 3 * 4;  // 3.1 MB
  int* pi    = (int*)p;    p += (size_t)Bb * Nn * NQ * 3 * 4;  // 3.1 MB

  const int prep_blocks = 4096 + (KT1 * RT * 64 + KT2 * RT * 64 + 255) / 256;
  prep_all_k<<<dim3(prep_blocks), dim3(256), 0, stream>>>(kf, kfTb, W1, W2, W1f, W2f);
  nn_quarter_k<<<dim3(Bb * 32 * NQ), dim3(256), 0, stream>>>(unknown, known, pd, pi);
  fused_gemm_k<<<dim3(Bb * (Nn / 64)), dim3(256), 0, stream>>>(
      uf, kfTb, W1f, b1, W2f, b2, pd, pi, out);
}

// Round 19
// 211.486 us; speedup vs baseline: 1.1802x; 1.0155x over previous
//
#include <hip/hip_runtime.h>

using bf16x8 = __attribute__((ext_vector_type(8))) short;
using f32x4  = __attribute__((ext_vector_type(4))) float;
using f32x2  = __attribute__((ext_vector_type(2))) float;

constexpr int Bb = 8, Nn = 8192, Mm = 2048, C1 = 128, C2 = 256, Hh = 256, K1 = 384;
constexpr int KT1 = K1 / 32;   // 12 k-tiles for GEMM1
constexpr int KT2 = Hh / 32;   // 8 k-tiles for GEMM2
constexpr int RT = Hh / 16;    // 16 row-tiles
constexpr int NQ = 4;          // nn: NQ=4 gated = 64.0us, best of 6 variants (R8..R14)
constexpr int MQ = Mm / NQ;    // 512 candidates per quarter

__device__ __forceinline__ short f2bf(float x) {  // RNE float->bf16
  union { float f; unsigned u; } v; v.f = x;
  unsigned r = v.u + 0x7fff + ((v.u >> 16) & 1);
  return (short)(r >> 16);
}

// packed RNE float2 -> 2x bf16 in one dword (hw instr when available)
__device__ __forceinline__ unsigned pk2bf(float a, float b) {
#if defined(__has_builtin) && __has_builtin(__builtin_amdgcn_cvt_pk_bf16_f32)
  typedef __attribute__((ext_vector_type(2))) __bf16 bf2_t;
  bf2_t r = __builtin_amdgcn_cvt_pk_bf16_f32(a, b);
  union { bf2_t v; unsigned u; } cvt; cvt.v = r;
  return cvt.u;
#else
  return (unsigned)(unsigned short)f2bf(a) | ((unsigned)(unsigned short)f2bf(b) << 16);
#endif
}

// unpack a dword holding 2 bf16 (lo = element 2i, hi = element 2i+1)
__device__ __forceinline__ float bflo(unsigned d) { return __uint_as_float(d << 16); }
__device__ __forceinline__ float bfhi(unsigned d) { return __uint_as_float(d & 0xffff0000u); }

// packed fp32 (CDNA3+). Lessons: feed ONLY from direct f32x2 loads (R9);
// two-pass recompute loses (R10); v_pk fp32 is throughput-neutral vs scalar
// (R13); 2-queries/thread loses TLP (R14). NQ=4 gated one-pass is the floor.
__device__ __forceinline__ f32x2 pk_add(f32x2 a, f32x2 b) {
  f32x2 d; asm("v_pk_add_f32 %0, %1, %2" : "=v"(d) : "v"(a), "v"(b)); return d;
}
__device__ __forceinline__ f32x2 pk_mul(f32x2 a, f32x2 b) {
  f32x2 d; asm("v_pk_mul_f32 %0, %1, %2" : "=v"(d) : "v"(a), "v"(b)); return d;
}
__device__ __forceinline__ f32x2 pk_fma(f32x2 a, f32x2 b, f32x2 c) {
  f32x2 d; asm("v_pk_fma_f32 %0, %1, %2, %3" : "=v"(d) : "v"(a), "v"(b), "v"(c)); return d;
}

// stable 2-list merge of sorted triples; ties prefer list a (lower global idx)
__device__ __forceinline__ void merge3(float a0, float a1, float a2, int A0, int A1, int A2,
                                       float b0, float b1, float b2, int B0, int B1, int B2,
                                       float& m0, float& m1, float& m2,
                                       int& j0, int& j1, int& j2) {
  bool ta = a0 <= b0;
  m0 = ta ? a0 : b0; j0 = ta ? A0 : B0;
  float na0 = ta ? a1 : a0, na1 = ta ? a2 : a1;
  int   nA0 = ta ? A1 : A0, nA1 = ta ? A2 : A1;
  float nb0 = ta ? b0 : b1, nb1 = ta ? b1 : b2;
  int   nB0 = ta ? B0 : B1, nB1 = ta ? B1 : B2;
  ta = na0 <= nb0;
  m1 = ta ? na0 : nb0; j1 = ta ? nA0 : nB0;
  float ma0 = ta ? na1 : na0; int mA0 = ta ? nA1 : nA0;
  float mb0 = ta ? nb0 : nb1; int mB0 = ta ? nB0 : nB1;
  ta = ma0 <= mb0;
  m2 = ta ? ma0 : mb0; j2 = ta ? mA0 : mB0;
}

// ------------- prep: kf transpose->bf16 (blocks 0..4095) + W frag prep -------------
// NOTE: prep, nn, fused stay SEPARATE kernels (R5/R6: fusing roles into one grid
// serialized the nn phase behind the transpose blocks, +40 us; launch overhead is
// fixed ~85 us regardless of kernel count — do not re-fuse).
__global__ __launch_bounds__(256) void prep_all_k(const float* __restrict__ kf,
                                                  short* __restrict__ kfTb,
                                                  const float* __restrict__ W1,
                                                  const float* __restrict__ W2,
                                                  short* __restrict__ W1f,
                                                  short* __restrict__ W2f) {
  __shared__ float tile[32][33];
  int bid = blockIdx.x, tid = threadIdx.x;
  if (bid < 4096) {  // transpose role: (B,C2,Mm) f32 -> (B,Mm,C2) bf16
    int cx = bid & 63, ry = (bid >> 6) & 7, z = bid >> 9;
    const float* src = kf + (size_t)z * C2 * Mm;
    short* dst = kfTb + (size_t)z * Mm * C2;
    int c0 = cx * 32, r0 = ry * 32;  // c0: point base, r0: channel base
    int tx = tid & 31, ty = tid >> 5;
#pragma unroll
    for (int rr = ty; rr < 32; rr += 8)
      tile[rr][tx] = src[(size_t)(r0 + rr) * Mm + c0 + tx];
    __syncthreads();
#pragma unroll
    for (int cc = ty; cc < 32; cc += 8)
      dst[(size_t)(c0 + cc) * C2 + r0 + tx] = f2bf(tile[tx][cc]);
    return;
  }
  // W-prep role: A-frag planes (lane holds A[m=lane&15][k0..k0+7], k0=(lane>>4)*8)
  int id = (bid - 4096) * 256 + tid;
  const int n1 = KT1 * RT * 64;
  const int n2 = KT2 * RT * 64;
  if (id < n1) {
    int lane = id & 63, t = id >> 6;
    int kt = t / RT, rt = t % RT;
    int m = rt * 16 + (lane & 15), k0 = kt * 32 + (lane >> 4) * 8;
    bf16x8 f;
#pragma unroll
    for (int j = 0; j < 8; ++j) f[j] = f2bf(W1[(size_t)m * K1 + k0 + j]);
    *(bf16x8*)(W1f + (size_t)id * 8) = f;
  } else if (id < n1 + n2) {
    int id2 = id - n1;
    int lane = id2 & 63, t = id2 >> 6;
    int kt = t / RT, rt = t % RT;
    int m = rt * 16 + (lane & 15), k0 = kt * 32 + (lane >> 4) * 8;
    bf16x8 f;
#pragma unroll
    for (int j = 0; j < 8; ++j) f[j] = f2bf(W2[(size_t)m * Hh + k0 + j]);
    *(bf16x8*)(W2f + (size_t)id2 * 8) = f;
  }
}

// ------------- three_nn over a quarter of the candidate set (R8-verbatim) -------------
// grid: b(8) x nblk(32) x q(4) = 1024 blocks of 256 -> 16 waves/CU (4/SIMD).
// Measured 64.0us (R8/R15/R17/R18) — best of 6 variants. Do not re-tune.
__global__ __launch_bounds__(256) void nn_quarter_k(const float* __restrict__ unknown,
                                                    const float* __restrict__ known,
                                                    float* __restrict__ pd,
                                                    int* __restrict__ pi) {
  __shared__ float kx[MQ], ky[MQ], kz[MQ];
  int bid = blockIdx.x;
  int b = bid >> 7, rem = bid & 127;
  int q = rem & 3, nblk = rem >> 2;
  int n = nblk * 256 + threadIdx.x;
  const float* kb = known + ((size_t)b * Mm + q * MQ) * 3;
  for (int p = threadIdx.x; p < MQ; p += 256) {
    kx[p] = kb[3 * p]; ky[p] = kb[3 * p + 1]; kz[p] = kb[3 * p + 2];
  }
  __syncthreads();

  size_t ui = ((size_t)b * Nn + n) * 3;
  float ux = unknown[ui], uy = unknown[ui + 1], uz = unknown[ui + 2];
  float d0 = 1e30f, d1 = 1e30f, d2 = 1e30f;
  int i0 = 0, i1 = 0, i2 = 0;
  int gbase = q * MQ;

  // broadcast negated query into packed pairs (once per thread)
  f32x2 nux = { -ux, -ux }, nuy = { -uy, -uy }, nuz = { -uz, -uz };

#define NN_INS(dd, qq)                                                  \
  {                                                                     \
    if (__any((dd) < d2)) { /* wave-uniform skip of the insert chain */ \
      int jm = gbase + jb + (qq);                                       \
      bool c0 = (dd) < d0, c1 = (dd) < d1, c2 = (dd) < d2;              \
      d2 = c1 ? d1 : (c2 ? (dd) : d2); i2 = c1 ? i1 : (c2 ? jm : i2);   \
      d1 = c0 ? d0 : (c1 ? (dd) : d1); i1 = c0 ? i0 : (c1 ? jm : i1);   \
      d0 = c0 ? (dd) : d0;             i0 = c0 ? jm : i0;               \
    }                                                                   \
  }

  const f32x2* kx2 = (const f32x2*)kx;
  const f32x2* ky2 = (const f32x2*)ky;
  const f32x2* kz2 = (const f32x2*)kz;
  for (int jb = 0; jb < MQ; jb += 4) {
    int h = jb >> 1;
    f32x2 xa = kx2[h], xb = kx2[h + 1];
    f32x2 ya = ky2[h], yb = ky2[h + 1];
    f32x2 za = kz2[h], zb = kz2[h + 1];
    // dd = (k-u)^2 summed; (k-u)^2 == (u-k)^2 bit-exact in fp32
    f32x2 dxa = pk_add(xa, nux), dya = pk_add(ya, nuy), dza = pk_add(za, nuz);
    f32x2 dda = pk_fma(dza, dza, pk_fma(dya, dya, pk_mul(dxa, dxa)));
    f32x2 dxb = pk_add(xb, nux), dyb = pk_add(yb, nuy), dzb = pk_add(zb, nuz);
    f32x2 ddb = pk_fma(dzb, dzb, pk_fma(dyb, dyb, pk_mul(dxb, dxb)));
    NN_INS(dda.x, 0)
    NN_INS(dda.y, 1)
    NN_INS(ddb.x, 2)
    NN_INS(ddb.y, 3)
  }
#undef NN_INS

  size_t o = (((size_t)b * Nn + n) * NQ + q) * 3;
  pd[o] = d0; pd[o + 1] = d1; pd[o + 2] = d2;
  pi[o] = i0; pi[o + 1] = i1; pi[o + 2] = i2;
}

// ------------- fused: 4-way merge -> gather+concat -> MLP1 -> MLP2 -> out -------------
// block = 256 thr (4 waves), 64 cols x 256 rows. grid = 8*128 = 1024 (R15 config;
// R16's 32-col split REGRESSED: fused is critical-path-bound, not TLP-bound).
// R19: 3-generation K1 pipeline — every gather load now rides under compute:
//   entry: pd/pi + ALL uf loads in flight -> merge -> pack uf (planes 0-3,
//   kt8-11) -> issue gather kt0-3 -> B1 -> K1(kt8-11) [kt0-3 flying] -> B2 ->
//   pack kt0-3 -> issue gather kt4-7 -> B3 -> K1(kt0-3) [kt4-7 flying] -> B4 ->
//   pack kt4-7 -> B5 -> K1(kt4-7) -> epilogue.
// LDS: 16KB 4-plane F buf + 32KB Hs overlay = 32KB -> 4 blocks/CU (unchanged).
// NOTE: K-sum order is now 8-11,0-3,4-7 (fp32 reorder, ~1ulp of partials —
// absmax may shift one quantum; if it FAILS, this reorder is the cause).
__global__ __launch_bounds__(256) void fused_gemm_k(
    const float* __restrict__ uf, const short* __restrict__ kfTb,
    const short* __restrict__ W1f, const float* __restrict__ b1,
    const short* __restrict__ W2f, const float* __restrict__ b2,
    const float* __restrict__ pd, const int* __restrict__ pi,
    float* __restrict__ out) {
  __shared__ short Fs[KT2 * 4 * 64 * 8];  // 32KB: Hs region for K2; head 16KB = 4-plane F buf
  short* Hs = Fs;
  int bid = blockIdx.x;
  int b = bid >> 7, bt = bid & 127;  // n0 = bt*64
  int tid = threadIdx.x, lane = tid & 63, wv = tid >> 6;
  int quad = lane >> 4, col = lane & 15;
  const int nq = bt * 64 + wv * 16 + col;  // this thread's point

  // ---- entry: issue pd/pi loads AND all uf loads together (independent)
  size_t pbase = (size_t)(b * Nn + nq) * (NQ * 3);  // stride 12 floats (48B), 16B-aligned
  float4 da = *(const float4*)&pd[pbase];
  float4 db = *(const float4*)&pd[pbase + 4];
  float4 dc = *(const float4*)&pd[pbase + 8];
  int4 ia = *(const int4*)&pi[pbase];
  int4 ib = *(const int4*)&pi[pbase + 4];
  int4 ic = *(const int4*)&pi[pbase + 8];
  float eu[4][8];
#pragma unroll
  for (int kt = 8; kt < 12; ++kt) {
    int c1 = (kt - 8) * 32 + quad * 8;
#pragma unroll
    for (int j = 0; j < 8; ++j)
      eu[kt - 8][j] = uf[((size_t)b * C1 + c1 + j) * Nn + nq];
  }

  // ---- merge: in-register 4-way NN merge (tree of 3 stable merges, R8 code).
  float w0, w1, w2;
  int g0, g1, g2;
  {
    float t0, t1, t2, u0, u1, u2, m0, m1, m2;
    int T0, T1, T2, U0, U1, U2;
    merge3(da.x, da.y, da.z, ia.x, ia.y, ia.z,
           da.w, db.x, db.y, ia.w, ib.x, ib.y, t0, t1, t2, T0, T1, T2);
    merge3(db.z, db.w, dc.x, ib.z, ib.w, ic.x,
           dc.y, dc.z, dc.w, ic.y, ic.z, ic.w, u0, u1, u2, U0, U1, U2);
    merge3(t0, t1, t2, T0, T1, T2, u0, u1, u2, U0, U1, U2,
           m0, m1, m2, g0, g1, g2);
    float s0 = sqrtf(m0), s1 = sqrtf(m1), s2 = sqrtf(m2);
    float r0 = 1.f / (s0 + 1e-8f), r1 = 1.f / (s1 + 1e-8f), r2 = 1.f / (s2 + 1e-8f);
    float rs = 1.f / (r0 + r1 + r2);
    w0 = r0 * rs; w1 = r1 * rs; w2 = r2 * rs;
  }
  const short* kfb = kfTb + (size_t)b * Mm * C2;

  // pack 3 gathered uint4 rows with interpolation weights into one B-frag store
#define PACK_STORE(q0, q1, q2, plane)                                         \
  {                                                                           \
    float e0 = w0 * bflo((q0).x) + w1 * bflo((q1).x) + w2 * bflo((q2).x);     \
    float e1 = w0 * bfhi((q0).x) + w1 * bfhi((q1).x) + w2 * bfhi((q2).x);     \
    float e2 = w0 * bflo((q0).y) + w1 * bflo((q1).y) + w2 * bflo((q2).y);     \
    float e3 = w0 * bfhi((q0).y) + w1 * bfhi((q1).y) + w2 * bfhi((q2).y);     \
    float e4 = w0 * bflo((q0).z) + w1 * bflo((q1).z) + w2 * bflo((q2).z);     \
    float e5 = w0 * bfhi((q0).z) + w1 * bfhi((q1).z) + w2 * bfhi((q2).z);     \
    float e6 = w0 * bflo((q0).w) + w1 * bflo((q1).w) + w2 * bflo((q2).w);     \
    float e7 = w0 * bfhi((q0).w) + w1 * bfhi((q1).w) + w2 * bfhi((q2).w);     \
    uint4 packed;                                                             \
    packed.x = pk2bf(e0, e1); packed.y = pk2bf(e2, e3);                       \
    packed.z = pk2bf(e4, e5); packed.w = pk2bf(e6, e7);                       \
    *(uint4*)&Fs[(((plane) * 4 + wv) * 64 + lane) * 8] = packed;              \
  }

  // ---- pack uf -> planes 0-3 (kt 8..11); uf loads have had merge time to land
#pragma unroll
  for (int kt = 8; kt < 12; ++kt) {
    uint4 packed;
    packed.x = pk2bf(eu[kt - 8][0], eu[kt - 8][1]);
    packed.y = pk2bf(eu[kt - 8][2], eu[kt - 8][3]);
    packed.z = pk2bf(eu[kt - 8][4], eu[kt - 8][5]);
    packed.w = pk2bf(eu[kt - 8][6], eu[kt - 8][7]);
    *(uint4*)&Fs[(((kt - 8) * 4 + wv) * 64 + lane) * 8] = packed;
  }

  // ---- issue gather kt0-3 into regs (flies under K1 gen-1)
  uint4 pa0, pa1, pa2, pa3, pa4, pa5, pa6, pa7, pa8, pa9, paA, paB;
  {
    int c0 = 0 * 32 + quad * 8, c1 = 1 * 32 + quad * 8;
    int c2 = 2 * 32 + quad * 8, c3 = 3 * 32 + quad * 8;
    pa0 = *(const uint4*)&kfb[(size_t)g0 * C2 + c0];
    pa1 = *(const uint4*)&kfb[(size_t)g1 * C2 + c0];
    pa2 = *(const uint4*)&kfb[(size_t)g2 * C2 + c0];
    pa3 = *(const uint4*)&kfb[(size_t)g0 * C2 + c1];
    pa4 = *(const uint4*)&kfb[(size_t)g1 * C2 + c1];
    pa5 = *(const uint4*)&kfb[(size_t)g2 * C2 + c1];
    pa6 = *(const uint4*)&kfb[(size_t)g0 * C2 + c2];
    pa7 = *(const uint4*)&kfb[(size_t)g1 * C2 + c2];
    pa8 = *(const uint4*)&kfb[(size_t)g2 * C2 + c2];
    pa9 = *(const uint4*)&kfb[(size_t)g0 * C2 + c3];
    paA = *(const uint4*)&kfb[(size_t)g1 * C2 + c3];
    paB = *(const uint4*)&kfb[(size_t)g2 * C2 + c3];
  }
  __syncthreads();  // B1: uf planes ready

  f32x4 acc[4][4];
#pragma unroll
  for (int r = 0; r < 4; ++r)
#pragma unroll
    for (int c = 0; c < 4; ++c) acc[r][c] = (f32x4){0.f, 0.f, 0.f, 0.f};

#define K1_GEN(KTBASE)                                                        \
  for (int ktl = 0; ktl < 4; ++ktl) {                                         \
    int kt = (KTBASE) + ktl;                                                  \
    bf16x8 Afr[4], Bfr[4];                                                    \
    _Pragma("unroll")                                                         \
    for (int r = 0; r < 4; ++r)                                               \
      Afr[r] = *(const bf16x8*)(W1f + ((size_t)(kt * RT + wv * 4 + r) * 64 + lane) * 8); \
    _Pragma("unroll")                                                         \
    for (int c = 0; c < 4; ++c)                                               \
      Bfr[c] = *(const bf16x8*)&Fs[((ktl * 4 + c) * 64 + lane) * 8];          \
    _Pragma("unroll")                                                         \
    for (int r = 0; r < 4; ++r)                                               \
      _Pragma("unroll")                                                       \
      for (int c = 0; c < 4; ++c)                                             \
        acc[r][c] = __builtin_amdgcn_mfma_f32_16x16x32_bf16(Afr[r], Bfr[c], acc[r][c], 0, 0, 0); \
  }

  // ---- K1 gen-1: kt 8..11 (uf planes) — gather kt0-3 in flight
  K1_GEN(8)
  __syncthreads();  // B2: gen-1 plane reads done

  // ---- pack gather kt0-3 -> planes 0-3; then issue gather kt4-7
  PACK_STORE(pa0, pa1, pa2, 0)
  PACK_STORE(pa3, pa4, pa5, 1)
  PACK_STORE(pa6, pa7, pa8, 2)
  PACK_STORE(pa9, paA, paB, 3)
  uint4 pb0, pb1, pb2, pb3, pb4, pb5, pb6, pb7, pb8, pb9, pbA, pbB;
  {
    int c4 = 4 * 32 + quad * 8, c5 = 5 * 32 + quad * 8;
    int c6 = 6 * 32 + quad * 8, c7 = 7 * 32 + quad * 8;
    pb0 = *(const uint4*)&kfb[(size_t)g0 * C2 + c4];
    pb1 = *(const uint4*)&kfb[(size_t)g1 * C2 + c4];
    pb2 = *(const uint4*)&kfb[(size_t)g2 * C2 + c4];
    pb3 = *(const uint4*)&kfb[(size_t)g0 * C2 + c5];
    pb4 = *(const uint4*)&kfb[(size_t)g1 * C2 + c5];
    pb5 = *(const uint4*)&kfb[(size_t)g2 * C2 + c5];
    pb6 = *(const uint4*)&kfb[(size_t)g0 * C2 + c6];
    pb7 = *(const uint4*)&kfb[(size_t)g1 * C2 + c6];
    pb8 = *(const uint4*)&kfb[(size_t)g2 * C2 + c6];
    pb9 = *(const uint4*)&kfb[(size_t)g0 * C2 + c7];
    pbA = *(const uint4*)&kfb[(size_t)g1 * C2 + c7];
    pbB = *(const uint4*)&kfb[(size_t)g2 * C2 + c7];
  }
  __syncthreads();  // B3: kt0-3 planes ready

  // ---- K1 gen-2: kt 0..3 — gather kt4-7 in flight
  K1_GEN(0)
  __syncthreads();  // B4: gen-2 plane reads done

  // ---- pack gather kt4-7 -> planes 0-3
  PACK_STORE(pb0, pb1, pb2, 0)
  PACK_STORE(pb3, pb4, pb5, 1)
  PACK_STORE(pb6, pb7, pb8, 2)
  PACK_STORE(pb9, pbA, pbB, 3)
  __syncthreads();  // B5: kt4-7 planes ready

  // ---- K1 gen-3: kt 4..7
  K1_GEN(4)
#undef K1_GEN
#undef PACK_STORE

  // ---- Epilogue 1: bias+relu in D-layout (regs only), then barrier, then
  // register bpermute D->B-frag into Hs.
#pragma unroll
  for (int r = 0; r < 4; ++r) {
    f32x4 bq = *(const f32x4*)&b1[wv * 64 + r * 16 + quad * 4];
#pragma unroll
    for (int c = 0; c < 4; ++c)
#pragma unroll
      for (int reg = 0; reg < 4; ++reg)
        acc[r][c][reg] = fmaxf(acc[r][c][reg] + bq[reg], 0.f);
  }
  __syncthreads();  // B6: gen-3 plane reads done; Hs (overlapping region) writable
  {
    int addr_lo = (((quad & 1) * 2) * 16 + col) * 4;  // src lane*4 for j<4
    bool hiSel = lane >= 32;
#pragma unroll
    for (int ktl = 0; ktl < 2; ++ktl)
#pragma unroll
      for (int c = 0; c < 4; ++c) {
        float e[8];
#pragma unroll
        for (int j = 0; j < 8; ++j) {
          int addr = addr_lo + (j >> 2) * 64;
          int lo = __builtin_amdgcn_ds_bpermute(addr, __float_as_int(acc[ktl * 2][c][j & 3]));
          int hi = __builtin_amdgcn_ds_bpermute(addr, __float_as_int(acc[ktl * 2 + 1][c][j & 3]));
          e[j] = __int_as_float(hiSel ? hi : lo);
        }
        uint4 packed;
        packed.x = pk2bf(e[0], e[1]); packed.y = pk2bf(e[2], e[3]);
        packed.z = pk2bf(e[4], e[5]); packed.w = pk2bf(e[6], e[7]);
        *(uint4*)&Hs[(((wv * 2 + ktl) * 4 + c) * 64 + lane) * 8] = packed;
      }
  }
  __syncthreads();  // B7: Hs ready

  // ---- K-loop 2
  f32x4 acc2[4][4];
#pragma unroll
  for (int r = 0; r < 4; ++r)
#pragma unroll
    for (int c = 0; c < 4; ++c) acc2[r][c] = (f32x4){0.f, 0.f, 0.f, 0.f};

  for (int kt = 0; kt < KT2; ++kt) {
    bf16x8 Afr[4], Bfr[4];
#pragma unroll
    for (int r = 0; r < 4; ++r)
      Afr[r] = *(const bf16x8*)(W2f + ((size_t)(kt * RT + wv * 4 + r) * 64 + lane) * 8);
#pragma unroll
    for (int c = 0; c < 4; ++c)
      Bfr[c] = *(const bf16x8*)&Hs[((kt * 4 + c) * 64 + lane) * 8];
#pragma unroll
    for (int r = 0; r < 4; ++r)
#pragma unroll
      for (int c = 0; c < 4; ++c)
        acc2[r][c] = __builtin_amdgcn_mfma_f32_16x16x32_bf16(Afr[r], Bfr[c], acc2[r][c], 0, 0, 0);
  }

  // ---- Epilogue 2: bias+relu, store
#pragma unroll
  for (int r = 0; r < 4; ++r) {
    f32x4 bq = *(const f32x4*)&b2[wv * 64 + r * 16 + quad * 4];
#pragma unroll
    for (int c = 0; c < 4; ++c)
#pragma unroll
      for (int reg = 0; reg < 4; ++reg) {
        int rowg = wv * 64 + r * 16 + quad * 4 + reg;
        int n = bt * 64 + c * 16 + col;
        out[((size_t)b * Hh + rowg) * Nn + n] = fmaxf(acc2[r][c][reg] + bq[reg], 0.f);
      }
  }
}

extern "C" void kernel_launch(void* const* d_in, const int* in_sizes, int n_in,
                              void* d_out, int out_size, void* d_ws, size_t ws_size,
                              hipStream_t stream) {
  const float* unknown = (const float*)d_in[0];
  const float* known   = (const float*)d_in[1];
  const float* uf      = (const float*)d_in[2];
  const float* kf      = (const float*)d_in[3];
  const float* W1      = (const float*)d_in[4];
  const float* b1      = (const float*)d_in[5];
  const float* W2      = (const float*)d_in[6];
  const float* b2      = (const float*)d_in[7];
  float* out = (float*)d_out;

  // ws layout (~16 MB)
  char* p = (char*)d_ws;
  short* kfTb = (short*)p; p += (size_t)Bb * Mm * C2 * 2;   // 8.4 MB bf16
  short* W1f = (short*)p;  p += (size_t)KT1 * RT * 64 * 8 * 2;
  short* W2f = (short*)p;  p += (size_t)KT2 * RT * 64 * 8 * 2;
  float* pd  = (float*)p;  p += (size_t)Bb * Nn * NQ * 3 * 4;  // 3.1 MB
  int* pi    = (int*)p;    p += (size_t)Bb * Nn * NQ * 3 * 4;  // 3.1 MB

  const int prep_blocks = 4096 + (KT1 * RT * 64 + KT2 * RT * 64 + 255) / 256;
  prep_all_k<<<dim3(prep_blocks), dim3(256), 0, stream>>>(kf, kfTb, W1, W2, W1f, W2f);
  nn_quarter_k<<<dim3(Bb * 32 * NQ), dim3(256), 0, stream>>>(unknown, known, pd, pi);
  fused_gemm_k<<<dim3(Bb * (Nn / 64)), dim3(256), 0, stream>>>(
      uf, kfTb, W1f, b1, W2f, b2, pd, pi, out);
}